// Round 1
// baseline (782.378 us; speedup 1.0000x reference)
//
#include <hip/hip_runtime.h>
#include <math.h>

// ---------------------------------------------------------------------------
// 3-layer GCN: h = celu(Agg(x)@W1+b1); h = celu(Agg(h)@W2+b2); out = celu(Agg(h@W3)+b3)
// Using linearity: Agg(x@W) == Agg(x)@W, so we aggregate in the smaller dim.
// Agg(r) = dinv[r] * ( h[r]*dinv[r] + sum_{s in N(r)} dinv[s]*h[s] )
// CSR built per call (ws is re-poisoned before every launch).
// ---------------------------------------------------------------------------

#define THREADS 256

__device__ __forceinline__ float celu1(float v) {
    return v > 0.0f ? v : expm1f(v);
}

// ---- CSR build ------------------------------------------------------------

__global__ __launch_bounds__(THREADS) void hist_kernel(
    const int* __restrict__ dst, int* __restrict__ cnt, int E) {
    int e = blockIdx.x * THREADS + threadIdx.x;
    if (e < E) atomicAdd(&cnt[dst[e]], 1);
}

// chunk = 1024 ints per block (4 per thread)
__global__ __launch_bounds__(THREADS) void scanA_kernel(
    const int* __restrict__ cnt, int* __restrict__ partials, int N) {
    __shared__ int s[THREADS];
    int i0 = blockIdx.x * 1024 + threadIdx.x * 4;
    int sum = 0;
#pragma unroll
    for (int j = 0; j < 4; ++j) {
        int i = i0 + j;
        if (i < N) sum += cnt[i];
    }
    s[threadIdx.x] = sum;
    __syncthreads();
    for (int off = THREADS / 2; off > 0; off >>= 1) {
        if (threadIdx.x < off) s[threadIdx.x] += s[threadIdx.x + off];
        __syncthreads();
    }
    if (threadIdx.x == 0) partials[blockIdx.x] = s[0];
}

__global__ void scanB_kernel(int* __restrict__ partials, int* __restrict__ rowptr,
                             int NB, int N) {
    if (threadIdx.x == 0 && blockIdx.x == 0) {
        int run = 0;
        for (int i = 0; i < NB; ++i) {
            int t = partials[i];
            partials[i] = run;
            run += t;
        }
        rowptr[N] = run;  // == E
    }
}

__global__ __launch_bounds__(THREADS) void scanC_kernel(
    const int* __restrict__ cnt, const int* __restrict__ partials,
    int* __restrict__ rowptr, int* __restrict__ cursor,
    float* __restrict__ dinv, int N) {
    __shared__ int s[THREADS];
    int base = partials[blockIdx.x];
    int i0 = blockIdx.x * 1024 + threadIdx.x * 4;
    int v[4];
    int sum = 0;
#pragma unroll
    for (int j = 0; j < 4; ++j) {
        int i = i0 + j;
        v[j] = (i < N) ? cnt[i] : 0;
        sum += v[j];
    }
    s[threadIdx.x] = sum;
    __syncthreads();
    // Hillis-Steele inclusive scan over thread sums
    for (int off = 1; off < THREADS; off <<= 1) {
        int t = 0;
        if ((int)threadIdx.x >= off) t = s[threadIdx.x - off];
        __syncthreads();
        if ((int)threadIdx.x >= off) s[threadIdx.x] += t;
        __syncthreads();
    }
    int run = base + s[threadIdx.x] - sum;  // exclusive prefix for this thread
#pragma unroll
    for (int j = 0; j < 4; ++j) {
        int i = i0 + j;
        if (i < N) {
            rowptr[i] = run;
            cursor[i] = run;
            dinv[i]   = rsqrtf((float)v[j] + 1.0f);  // +1 self-loop
            run += v[j];
        }
    }
}

__global__ __launch_bounds__(THREADS) void scatter_kernel(
    const int* __restrict__ src, const int* __restrict__ dst,
    int* __restrict__ cursor, int* __restrict__ col, int E) {
    int e = blockIdx.x * THREADS + threadIdx.x;
    if (e < E) {
        int d = dst[e];
        int pos = atomicAdd(&cursor[d], 1);
        col[pos] = src[e];
    }
}

// ---- Aggregation (gather SpMM): one wave per row --------------------------

template <int F, bool ACT>
__global__ __launch_bounds__(THREADS) void agg_kernel(
    const float* __restrict__ h, const int* __restrict__ rowptr,
    const int* __restrict__ col, const float* __restrict__ dinv,
    const float* __restrict__ bias, float* __restrict__ out, int N) {
    const int lane = threadIdx.x & 63;
    const int r = blockIdx.x * 4 + (threadIdx.x >> 6);
    if (r >= N) return;
    const float dr = dinv[r];
    const int start = rowptr[r];
    const int end   = rowptr[r + 1];

    if constexpr (F == 128) {
        const float2* h2 = (const float2*)h;
        float2 acc = h2[(size_t)r * 64 + lane];  // self-loop term
        acc.x *= dr; acc.y *= dr;
        for (int b = start; b < end; b += 64) {
            int m = end - b; if (m > 64) m = 64;
            int c = 0; float w = 0.0f;
            if (lane < m) { c = col[b + lane]; w = dinv[c]; }
            for (int j = 0; j < m; ++j) {
                int cj  = __shfl(c, j);
                float wj = __shfl(w, j);
                float2 hv = h2[(size_t)cj * 64 + lane];
                acc.x += wj * hv.x;
                acc.y += wj * hv.y;
            }
        }
        float2 res;
        res.x = acc.x * dr;
        res.y = acc.y * dr;
        if constexpr (ACT) {
            float2 bv = ((const float2*)bias)[lane];
            res.x = celu1(res.x + bv.x);
            res.y = celu1(res.y + bv.y);
        }
        ((float2*)out)[(size_t)r * 64 + lane] = res;
    } else {  // F == 64
        float acc = h[(size_t)r * 64 + lane] * dr;
        for (int b = start; b < end; b += 64) {
            int m = end - b; if (m > 64) m = 64;
            int c = 0; float w = 0.0f;
            if (lane < m) { c = col[b + lane]; w = dinv[c]; }
            for (int j = 0; j < m; ++j) {
                int cj  = __shfl(c, j);
                float wj = __shfl(w, j);
                acc += wj * h[(size_t)cj * 64 + lane];
            }
        }
        float res = acc * dr;
        if constexpr (ACT) res = celu1(res + bias[lane]);
        out[(size_t)r * 64 + lane] = res;
    }
}

// ---- Dense transform: out[N,F] = act(X[N,K] @ W[K,F] + b) -----------------
// Block: 256 threads, 32 rows. W staged in <=32KB k-tiles, X tile in LDS.

template <int K, int F, bool ACT>
__global__ __launch_bounds__(THREADS) void gemm_kernel(
    const float* __restrict__ X, const float* __restrict__ W,
    const float* __restrict__ bias, float* __restrict__ out, int N) {
    constexpr int ROWS = 32;
    constexpr int KT   = (K > 64) ? 64 : K;       // k-tile
    constexpr int NF4  = F / 4;                    // float4 groups along F
    constexpr int G    = THREADS / NF4;            // row groups
    constexpr int RPT  = ROWS / G;                 // rows per thread
    __shared__ float Ws[KT * F];
    __shared__ float Xs[ROWS * K];

    const int tid  = threadIdx.x;
    const int row0 = blockIdx.x * ROWS;
    if (row0 >= N) return;

    // load X tile (rows are contiguous)
    const float4* Xg = (const float4*)(X + (size_t)row0 * K);
    for (int i = tid; i < ROWS * K / 4; i += THREADS)
        ((float4*)Xs)[i] = Xg[i];

    const int fg = tid % NF4;
    const int rg = tid / NF4;
    float4 acc[RPT];
#pragma unroll
    for (int j = 0; j < RPT; ++j) acc[j] = make_float4(0.f, 0.f, 0.f, 0.f);

    for (int kt = 0; kt < K; kt += KT) {
        __syncthreads();
        const float4* Wg = (const float4*)(W + (size_t)kt * F);
        for (int i = tid; i < KT * F / 4; i += THREADS)
            ((float4*)Ws)[i] = Wg[i];
        __syncthreads();
#pragma unroll 4
        for (int k = 0; k < KT; k += 4) {
            float4 xv[RPT];
#pragma unroll
            for (int j = 0; j < RPT; ++j)
                xv[j] = *(const float4*)&Xs[(rg + j * G) * K + kt + k];
#pragma unroll
            for (int kk = 0; kk < 4; ++kk) {
                float4 wv = *(const float4*)&Ws[(k + kk) * F + fg * 4];
#pragma unroll
                for (int j = 0; j < RPT; ++j) {
                    float xs = ((const float*)&xv[j])[kk];
                    acc[j].x += xs * wv.x;
                    acc[j].y += xs * wv.y;
                    acc[j].z += xs * wv.z;
                    acc[j].w += xs * wv.w;
                }
            }
        }
    }

#pragma unroll
    for (int j = 0; j < RPT; ++j) {
        float4 v = acc[j];
        if constexpr (ACT) {
            float4 bv = ((const float4*)bias)[fg];
            v.x = celu1(v.x + bv.x);
            v.y = celu1(v.y + bv.y);
            v.z = celu1(v.z + bv.z);
            v.w = celu1(v.w + bv.w);
        }
        int r = row0 + rg + j * G;
        *(float4*)&out[(size_t)r * F + fg * 4] = v;
    }
}

// ---------------------------------------------------------------------------

extern "C" void kernel_launch(void* const* d_in, const int* in_sizes, int n_in,
                              void* d_out, int out_size, void* d_ws, size_t ws_size,
                              hipStream_t stream) {
    const float* x  = (const float*)d_in[0];
    const int*   ei = (const int*)d_in[1];
    const float* W1 = (const float*)d_in[2];
    const float* b1 = (const float*)d_in[3];
    const float* W2 = (const float*)d_in[4];
    const float* b2 = (const float*)d_in[5];
    const float* W3 = (const float*)d_in[6];
    const float* b3 = (const float*)d_in[7];
    float* out = (float*)d_out;

    const int N = in_sizes[0] / 64;   // 100000
    const int E = in_sizes[1] / 2;    // 1600000
    const int* src = ei;
    const int* dst = ei + E;

    // workspace carve (all 256B-aligned)
    char* p = (char*)d_ws;
    auto carve = [&](size_t bytes) {
        void* q = p;
        p += (bytes + 255) & ~(size_t)255;
        return q;
    };
    int*   cnt      = (int*)carve((size_t)N * sizeof(int));
    int*   rowptr   = (int*)carve((size_t)(N + 1) * sizeof(int));
    int*   cursor   = (int*)carve((size_t)N * sizeof(int));
    int*   col      = (int*)carve((size_t)E * sizeof(int));
    float* dinv     = (float*)carve((size_t)N * sizeof(float));
    int*   partials = (int*)carve(1024 * sizeof(int));
    float* B1       = (float*)carve((size_t)N * 128 * sizeof(float));
    float* B2       = (float*)carve((size_t)N * 128 * sizeof(float));

    const int NB = (N + 1023) / 1024;
    const int EB = (E + THREADS - 1) / THREADS;
    const int AB = (N + 3) / 4;        // agg blocks (wave per row, 4 waves/block)
    const int GB = (N + 31) / 32;      // gemm blocks (32 rows/block)

    // --- CSR build (ws is poisoned before each call; rebuild every time) ---
    hipMemsetAsync(cnt, 0, (size_t)N * sizeof(int), stream);
    hist_kernel<<<EB, THREADS, 0, stream>>>(dst, cnt, E);
    scanA_kernel<<<NB, THREADS, 0, stream>>>(cnt, partials, N);
    scanB_kernel<<<1, 64, 0, stream>>>(partials, rowptr, NB, N);
    scanC_kernel<<<NB, THREADS, 0, stream>>>(cnt, partials, rowptr, cursor, dinv, N);
    scatter_kernel<<<EB, THREADS, 0, stream>>>(src, dst, cursor, col, E);

    // --- Layer 1: a1 = celu(Agg(x) @ W1 + b1) ---
    agg_kernel<64, false><<<AB, THREADS, 0, stream>>>(x, rowptr, col, dinv, nullptr, B1, N);
    gemm_kernel<64, 128, true><<<GB, THREADS, 0, stream>>>(B1, W1, b1, B2, N);

    // --- Layer 2: a2 = celu(Agg(a1) @ W2 + b2) ---
    agg_kernel<128, false><<<AB, THREADS, 0, stream>>>(B2, rowptr, col, dinv, nullptr, B1, N);
    gemm_kernel<128, 128, true><<<GB, THREADS, 0, stream>>>(B1, W2, b2, B2, N);

    // --- Layer 3: out = celu(Agg(a2 @ W3) + b3) ---
    gemm_kernel<128, 64, false><<<GB, THREADS, 0, stream>>>(B2, W3, nullptr, B1, N);
    agg_kernel<64, true><<<AB, THREADS, 0, stream>>>(B1, rowptr, col, dinv, b3, out, N);
}

// Round 2
// 673.229 us; speedup vs baseline: 1.1621x; 1.1621x over previous
//
#include <hip/hip_runtime.h>
#include <math.h>

// ---------------------------------------------------------------------------
// 3-layer GCN: h = celu(Agg(x)@W1+b1); h = celu(Agg(h)@W2+b2); out = celu(Agg(h@W3)+b3)
// Agg(r) = dinv[r] * ( h[r]*dinv[r] + sum_{s in N(r)} dinv[s]*h[s] )
// CSR built per call (ws is re-poisoned before every launch).
// R1: multi-edge-per-iteration gather (float4 per lane, 4 edges/iter @F=64,
//     2 edges/iter @F=128) to attack the memory-latency bound seen in R0.
// ---------------------------------------------------------------------------

#define THREADS 256

__device__ __forceinline__ float celu1(float v) {
    return v > 0.0f ? v : expm1f(v);
}

// ---- CSR build ------------------------------------------------------------

__global__ __launch_bounds__(THREADS) void hist_kernel(
    const int* __restrict__ dst, int* __restrict__ cnt, int E) {
    int e = blockIdx.x * THREADS + threadIdx.x;
    if (e < E) atomicAdd(&cnt[dst[e]], 1);
}

// chunk = 1024 ints per block (4 per thread)
__global__ __launch_bounds__(THREADS) void scanA_kernel(
    const int* __restrict__ cnt, int* __restrict__ partials, int N) {
    __shared__ int s[THREADS];
    int i0 = blockIdx.x * 1024 + threadIdx.x * 4;
    int sum = 0;
#pragma unroll
    for (int j = 0; j < 4; ++j) {
        int i = i0 + j;
        if (i < N) sum += cnt[i];
    }
    s[threadIdx.x] = sum;
    __syncthreads();
    for (int off = THREADS / 2; off > 0; off >>= 1) {
        if (threadIdx.x < off) s[threadIdx.x] += s[threadIdx.x + off];
        __syncthreads();
    }
    if (threadIdx.x == 0) partials[blockIdx.x] = s[0];
}

__global__ void scanB_kernel(int* __restrict__ partials, int* __restrict__ rowptr,
                             int NB, int N) {
    if (threadIdx.x == 0 && blockIdx.x == 0) {
        int run = 0;
        for (int i = 0; i < NB; ++i) {
            int t = partials[i];
            partials[i] = run;
            run += t;
        }
        rowptr[N] = run;  // == E
    }
}

__global__ __launch_bounds__(THREADS) void scanC_kernel(
    const int* __restrict__ cnt, const int* __restrict__ partials,
    int* __restrict__ rowptr, int* __restrict__ cursor,
    float* __restrict__ dinv, int N) {
    __shared__ int s[THREADS];
    int base = partials[blockIdx.x];
    int i0 = blockIdx.x * 1024 + threadIdx.x * 4;
    int v[4];
    int sum = 0;
#pragma unroll
    for (int j = 0; j < 4; ++j) {
        int i = i0 + j;
        v[j] = (i < N) ? cnt[i] : 0;
        sum += v[j];
    }
    s[threadIdx.x] = sum;
    __syncthreads();
    // Hillis-Steele inclusive scan over thread sums
    for (int off = 1; off < THREADS; off <<= 1) {
        int t = 0;
        if ((int)threadIdx.x >= off) t = s[threadIdx.x - off];
        __syncthreads();
        if ((int)threadIdx.x >= off) s[threadIdx.x] += t;
        __syncthreads();
    }
    int run = base + s[threadIdx.x] - sum;  // exclusive prefix for this thread
#pragma unroll
    for (int j = 0; j < 4; ++j) {
        int i = i0 + j;
        if (i < N) {
            rowptr[i] = run;
            cursor[i] = run;
            dinv[i]   = rsqrtf((float)v[j] + 1.0f);  // +1 self-loop
            run += v[j];
        }
    }
}

__global__ __launch_bounds__(THREADS) void scatter_kernel(
    const int* __restrict__ src, const int* __restrict__ dst,
    int* __restrict__ cursor, int* __restrict__ col, int E) {
    int e = blockIdx.x * THREADS + threadIdx.x;
    if (e < E) {
        int d = dst[e];
        int pos = atomicAdd(&cursor[d], 1);
        col[pos] = src[e];
    }
}

// ---- Aggregation F=64: wave per row, 4 edges/iter, float4 per lane --------

template <bool ACT>
__global__ __launch_bounds__(THREADS) void agg64_kernel(
    const float* __restrict__ h, const int* __restrict__ rowptr,
    const int* __restrict__ col, const float* __restrict__ dinv,
    const float* __restrict__ bias, float* __restrict__ out, int N) {
    const int lane = threadIdx.x & 63;
    const int r = blockIdx.x * 4 + (threadIdx.x >> 6);
    if (r >= N) return;
    const int quad = lane >> 4;   // which of 4 concurrent edges
    const int sub  = lane & 15;   // feature group (4 floats)
    const float4* __restrict__ h4 = (const float4*)h;
    const float dr = dinv[r];
    const int start = rowptr[r];
    const int end   = rowptr[r + 1];

    float4 acc = make_float4(0.f, 0.f, 0.f, 0.f);
    if (quad == 0) {  // self-loop term dr*h[r]
        float4 hv = h4[(size_t)r * 16 + sub];
        acc.x = dr * hv.x; acc.y = dr * hv.y;
        acc.z = dr * hv.z; acc.w = dr * hv.w;
    }

    for (int b = start; b < end; b += 64) {
        int m = end - b; if (m > 64) m = 64;
        int c = 0; float w = 0.0f;
        if (lane < m) { c = col[b + lane]; w = dinv[c]; }
        // lanes >= m hold c=0,w=0, so tail slots are free (weight-0 row 0)
#pragma unroll 2
        for (int j = 0; j < m; j += 4) {
            int   cj = __shfl(c, j + quad);
            float wj = __shfl(w, j + quad);
            float4 hv = h4[(size_t)cj * 16 + sub];
            acc.x += wj * hv.x; acc.y += wj * hv.y;
            acc.z += wj * hv.z; acc.w += wj * hv.w;
        }
    }

    // reduce the 4 quad-partials
#pragma unroll
    for (int off = 32; off >= 16; off >>= 1) {
        acc.x += __shfl_xor(acc.x, off);
        acc.y += __shfl_xor(acc.y, off);
        acc.z += __shfl_xor(acc.z, off);
        acc.w += __shfl_xor(acc.w, off);
    }

    if (quad == 0) {
        float4 res;
        res.x = acc.x * dr; res.y = acc.y * dr;
        res.z = acc.z * dr; res.w = acc.w * dr;
        if constexpr (ACT) {
            float4 bv = ((const float4*)bias)[sub];
            res.x = celu1(res.x + bv.x);
            res.y = celu1(res.y + bv.y);
            res.z = celu1(res.z + bv.z);
            res.w = celu1(res.w + bv.w);
        }
        ((float4*)out)[(size_t)r * 16 + sub] = res;
    }
}

// ---- Aggregation F=128: wave per row, 2 edges/iter, float4 per lane -------

__global__ __launch_bounds__(THREADS) void agg128_kernel(
    const float* __restrict__ h, const int* __restrict__ rowptr,
    const int* __restrict__ col, const float* __restrict__ dinv,
    float* __restrict__ out, int N) {
    const int lane = threadIdx.x & 63;
    const int r = blockIdx.x * 4 + (threadIdx.x >> 6);
    if (r >= N) return;
    const int half = lane >> 5;   // which of 2 concurrent edges
    const int sub  = lane & 31;   // feature group (4 floats)
    const float4* __restrict__ h4 = (const float4*)h;
    const float dr = dinv[r];
    const int start = rowptr[r];
    const int end   = rowptr[r + 1];

    float4 acc = make_float4(0.f, 0.f, 0.f, 0.f);
    if (half == 0) {  // self-loop
        float4 hv = h4[(size_t)r * 32 + sub];
        acc.x = dr * hv.x; acc.y = dr * hv.y;
        acc.z = dr * hv.z; acc.w = dr * hv.w;
    }

    for (int b = start; b < end; b += 64) {
        int m = end - b; if (m > 64) m = 64;
        int c = 0; float w = 0.0f;
        if (lane < m) { c = col[b + lane]; w = dinv[c]; }
#pragma unroll 2
        for (int j = 0; j < m; j += 2) {
            int   cj = __shfl(c, j + half);
            float wj = __shfl(w, j + half);
            float4 hv = h4[(size_t)cj * 32 + sub];
            acc.x += wj * hv.x; acc.y += wj * hv.y;
            acc.z += wj * hv.z; acc.w += wj * hv.w;
        }
    }

    // reduce the 2 half-partials
    acc.x += __shfl_xor(acc.x, 32);
    acc.y += __shfl_xor(acc.y, 32);
    acc.z += __shfl_xor(acc.z, 32);
    acc.w += __shfl_xor(acc.w, 32);

    if (half == 0) {
        float4 res;
        res.x = acc.x * dr; res.y = acc.y * dr;
        res.z = acc.z * dr; res.w = acc.w * dr;
        ((float4*)out)[(size_t)r * 32 + sub] = res;
    }
}

// ---- Dense transform: out[N,F] = act(X[N,K] @ W[K,F] + b) -----------------

template <int K, int F, bool ACT>
__global__ __launch_bounds__(THREADS) void gemm_kernel(
    const float* __restrict__ X, const float* __restrict__ W,
    const float* __restrict__ bias, float* __restrict__ out, int N) {
    constexpr int ROWS = 32;
    constexpr int KT   = (K > 64) ? 64 : K;       // k-tile
    constexpr int NF4  = F / 4;                    // float4 groups along F
    constexpr int G    = THREADS / NF4;            // row groups
    constexpr int RPT  = ROWS / G;                 // rows per thread
    __shared__ float Ws[KT * F];
    __shared__ float Xs[ROWS * K];

    const int tid  = threadIdx.x;
    const int row0 = blockIdx.x * ROWS;
    if (row0 >= N) return;

    const float4* Xg = (const float4*)(X + (size_t)row0 * K);
    for (int i = tid; i < ROWS * K / 4; i += THREADS)
        ((float4*)Xs)[i] = Xg[i];

    const int fg = tid % NF4;
    const int rg = tid / NF4;
    float4 acc[RPT];
#pragma unroll
    for (int j = 0; j < RPT; ++j) acc[j] = make_float4(0.f, 0.f, 0.f, 0.f);

    for (int kt = 0; kt < K; kt += KT) {
        __syncthreads();
        const float4* Wg = (const float4*)(W + (size_t)kt * F);
        for (int i = tid; i < KT * F / 4; i += THREADS)
            ((float4*)Ws)[i] = Wg[i];
        __syncthreads();
#pragma unroll 4
        for (int k = 0; k < KT; k += 4) {
            float4 xv[RPT];
#pragma unroll
            for (int j = 0; j < RPT; ++j)
                xv[j] = *(const float4*)&Xs[(rg + j * G) * K + kt + k];
#pragma unroll
            for (int kk = 0; kk < 4; ++kk) {
                float4 wv = *(const float4*)&Ws[(k + kk) * F + fg * 4];
#pragma unroll
                for (int j = 0; j < RPT; ++j) {
                    float xs = ((const float*)&xv[j])[kk];
                    acc[j].x += xs * wv.x;
                    acc[j].y += xs * wv.y;
                    acc[j].z += xs * wv.z;
                    acc[j].w += xs * wv.w;
                }
            }
        }
    }

#pragma unroll
    for (int j = 0; j < RPT; ++j) {
        float4 v = acc[j];
        if constexpr (ACT) {
            float4 bv = ((const float4*)bias)[fg];
            v.x = celu1(v.x + bv.x);
            v.y = celu1(v.y + bv.y);
            v.z = celu1(v.z + bv.z);
            v.w = celu1(v.w + bv.w);
        }
        int r = row0 + rg + j * G;
        *(float4*)&out[(size_t)r * F + fg * 4] = v;
    }
}

// ---------------------------------------------------------------------------

extern "C" void kernel_launch(void* const* d_in, const int* in_sizes, int n_in,
                              void* d_out, int out_size, void* d_ws, size_t ws_size,
                              hipStream_t stream) {
    const float* x  = (const float*)d_in[0];
    const int*   ei = (const int*)d_in[1];
    const float* W1 = (const float*)d_in[2];
    const float* b1 = (const float*)d_in[3];
    const float* W2 = (const float*)d_in[4];
    const float* b2 = (const float*)d_in[5];
    const float* W3 = (const float*)d_in[6];
    const float* b3 = (const float*)d_in[7];
    float* out = (float*)d_out;

    const int N = in_sizes[0] / 64;   // 100000
    const int E = in_sizes[1] / 2;    // 1600000
    const int* src = ei;
    const int* dst = ei + E;

    // workspace carve (all 256B-aligned)
    char* p = (char*)d_ws;
    auto carve = [&](size_t bytes) {
        void* q = p;
        p += (bytes + 255) & ~(size_t)255;
        return q;
    };
    int*   cnt      = (int*)carve((size_t)N * sizeof(int));
    int*   rowptr   = (int*)carve((size_t)(N + 1) * sizeof(int));
    int*   cursor   = (int*)carve((size_t)N * sizeof(int));
    int*   col      = (int*)carve((size_t)E * sizeof(int));
    float* dinv     = (float*)carve((size_t)N * sizeof(float));
    int*   partials = (int*)carve(1024 * sizeof(int));
    float* B1       = (float*)carve((size_t)N * 128 * sizeof(float));
    float* B2       = (float*)carve((size_t)N * 128 * sizeof(float));

    const int NB = (N + 1023) / 1024;
    const int EB = (E + THREADS - 1) / THREADS;
    const int AB = (N + 3) / 4;        // agg blocks (wave per row, 4 waves/block)
    const int GB = (N + 31) / 32;      // gemm blocks (32 rows/block)

    // --- CSR build ---
    hipMemsetAsync(cnt, 0, (size_t)N * sizeof(int), stream);
    hist_kernel<<<EB, THREADS, 0, stream>>>(dst, cnt, E);
    scanA_kernel<<<NB, THREADS, 0, stream>>>(cnt, partials, N);
    scanB_kernel<<<1, 64, 0, stream>>>(partials, rowptr, NB, N);
    scanC_kernel<<<NB, THREADS, 0, stream>>>(cnt, partials, rowptr, cursor, dinv, N);
    scatter_kernel<<<EB, THREADS, 0, stream>>>(src, dst, cursor, col, E);

    // --- Layer 1: a1 = celu(Agg(x) @ W1 + b1) ---
    agg64_kernel<false><<<AB, THREADS, 0, stream>>>(x, rowptr, col, dinv, nullptr, B1, N);
    gemm_kernel<64, 128, true><<<GB, THREADS, 0, stream>>>(B1, W1, b1, B2, N);

    // --- Layer 2: a2 = celu(Agg(a1) @ W2 + b2) ---
    agg128_kernel<<<AB, THREADS, 0, stream>>>(B2, rowptr, col, dinv, B1, N);
    gemm_kernel<128, 128, true><<<GB, THREADS, 0, stream>>>(B1, W2, b2, B2, N);

    // --- Layer 3: out = celu(Agg(a2 @ W3) + b3) ---
    gemm_kernel<128, 64, false><<<GB, THREADS, 0, stream>>>(B2, W3, nullptr, B1, N);
    agg64_kernel<true><<<AB, THREADS, 0, stream>>>(B1, rowptr, col, dinv, b3, out, N);
}

// Round 3
// 652.628 us; speedup vs baseline: 1.1988x; 1.0316x over previous
//
#include <hip/hip_runtime.h>
#include <math.h>

// ---------------------------------------------------------------------------
// 3-layer GCN: h = celu(Agg(x)@W1+b1); h = celu(Agg(h)@W2+b2); out = celu(Agg(h@W3)+b3)
// Agg(r) = dinv[r] * ( h[r]*dinv[r] + sum_{s in N(r)} dinv[s]*h[s] )
// R2: CSR build via locality-bucketed counting sort (dst>>10 buckets) —
//     replaces the random-scatter (105MB partial-line writebacks, 127us) and
//     the random-atomic hist. All random accesses now hit <=64KB hot windows.
// ---------------------------------------------------------------------------

#define THREADS 256
#define BSHIFT 10              // nodes per bucket = 1024
#define NBUCK_MAX 128
#define EPT 16                 // edges per thread in bucket_scatter
#define CHUNK (THREADS * EPT)  // 4096 edges per block

__device__ __forceinline__ float celu1(float v) {
    return v > 0.0f ? v : expm1f(v);
}

// ---- CSR build: bucketed counting sort ------------------------------------

__global__ __launch_bounds__(THREADS) void bucket_hist_kernel(
    const int* __restrict__ dst, int* __restrict__ bucketCnt, int E, int NBUCK) {
    __shared__ int lcnt[NBUCK_MAX];
    if (threadIdx.x < NBUCK_MAX) lcnt[threadIdx.x] = 0;
    __syncthreads();
    for (int e = blockIdx.x * THREADS + threadIdx.x; e < E; e += gridDim.x * THREADS)
        atomicAdd(&lcnt[dst[e] >> BSHIFT], 1);
    __syncthreads();
    if (threadIdx.x < NBUCK && lcnt[threadIdx.x])
        atomicAdd(&bucketCnt[threadIdx.x], lcnt[threadIdx.x]);
}

__global__ void bucket_scan_kernel(const int* __restrict__ bucketCnt,
                                   int* __restrict__ bucketOff,
                                   int* __restrict__ bucketCur, int NBUCK, int E) {
    if (threadIdx.x == 0) {
        int run = 0;
        for (int b = 0; b < NBUCK; ++b) {
            bucketOff[b] = run;
            bucketCur[b] = run;
            run += bucketCnt[b];
        }
        bucketOff[NBUCK] = run;  // == E
    }
}

__global__ __launch_bounds__(THREADS) void bucket_scatter_kernel(
    const int* __restrict__ src, const int* __restrict__ dst,
    int* __restrict__ bucketCur, int2* __restrict__ ePair, int E) {
    __shared__ int lcnt[NBUCK_MAX];
    __shared__ int lbase[NBUCK_MAX];
    if (threadIdx.x < NBUCK_MAX) lcnt[threadIdx.x] = 0;
    __syncthreads();
    const int base = blockIdx.x * CHUNK;
    int bk[EPT], rk[EPT], dd[EPT], ss[EPT];
#pragma unroll
    for (int i = 0; i < EPT; ++i) {
        int e = base + i * THREADS + threadIdx.x;
        if (e < E) {
            dd[i] = dst[e];
            ss[i] = src[e];
            bk[i] = dd[i] >> BSHIFT;
            rk[i] = atomicAdd(&lcnt[bk[i]], 1);
        } else {
            bk[i] = -1;
        }
    }
    __syncthreads();
    if (threadIdx.x < NBUCK_MAX && lcnt[threadIdx.x])
        lbase[threadIdx.x] = atomicAdd(&bucketCur[threadIdx.x], lcnt[threadIdx.x]);
    __syncthreads();
#pragma unroll
    for (int i = 0; i < EPT; ++i) {
        if (bk[i] >= 0) {
            int p = lbase[bk[i]] + rk[i];
            ePair[p] = make_int2(dd[i], ss[i]);
        }
    }
}

// per-bucket node histogram via LDS counters (replaces global-atomic hist)
__global__ __launch_bounds__(THREADS) void node_hist_kernel(
    const int2* __restrict__ ePair, const int* __restrict__ bucketOff,
    int* __restrict__ cnt, int N) {
    __shared__ int hcnt[1 << BSHIFT];
    const int b    = blockIdx.x >> 2;
    const int part = blockIdx.x & 3;
    for (int i = threadIdx.x; i < (1 << BSHIFT); i += THREADS) hcnt[i] = 0;
    __syncthreads();
    const int off = bucketOff[b];
    const int len = bucketOff[b + 1] - off;
    const int lo  = off + (int)(((long long)len * part) >> 2);
    const int hi  = off + (int)(((long long)len * (part + 1)) >> 2);
    for (int e = lo + threadIdx.x; e < hi; e += THREADS)
        atomicAdd(&hcnt[ePair[e].x & ((1 << BSHIFT) - 1)], 1);
    __syncthreads();
    const int node0 = b << BSHIFT;
    for (int i = threadIdx.x; i < (1 << BSHIFT); i += THREADS) {
        int node = node0 + i;
        if (node < N && hcnt[i]) atomicAdd(&cnt[node], hcnt[i]);
    }
}

// chunk = 1024 ints per block (4 per thread)
__global__ __launch_bounds__(THREADS) void scanA_kernel(
    const int* __restrict__ cnt, int* __restrict__ partials, int N) {
    __shared__ int s[THREADS];
    int i0 = blockIdx.x * 1024 + threadIdx.x * 4;
    int sum = 0;
#pragma unroll
    for (int j = 0; j < 4; ++j) {
        int i = i0 + j;
        if (i < N) sum += cnt[i];
    }
    s[threadIdx.x] = sum;
    __syncthreads();
    for (int off = THREADS / 2; off > 0; off >>= 1) {
        if (threadIdx.x < off) s[threadIdx.x] += s[threadIdx.x + off];
        __syncthreads();
    }
    if (threadIdx.x == 0) partials[blockIdx.x] = s[0];
}

__global__ void scanB_kernel(int* __restrict__ partials, int* __restrict__ rowptr,
                             int NB, int N) {
    if (threadIdx.x == 0 && blockIdx.x == 0) {
        int run = 0;
        for (int i = 0; i < NB; ++i) {
            int t = partials[i];
            partials[i] = run;
            run += t;
        }
        rowptr[N] = run;  // == E
    }
}

__global__ __launch_bounds__(THREADS) void scanC_kernel(
    const int* __restrict__ cnt, const int* __restrict__ partials,
    int* __restrict__ rowptr, int* __restrict__ cursor,
    float* __restrict__ dinv, int N) {
    __shared__ int s[THREADS];
    int base = partials[blockIdx.x];
    int i0 = blockIdx.x * 1024 + threadIdx.x * 4;
    int v[4];
    int sum = 0;
#pragma unroll
    for (int j = 0; j < 4; ++j) {
        int i = i0 + j;
        v[j] = (i < N) ? cnt[i] : 0;
        sum += v[j];
    }
    s[threadIdx.x] = sum;
    __syncthreads();
    for (int off = 1; off < THREADS; off <<= 1) {
        int t = 0;
        if ((int)threadIdx.x >= off) t = s[threadIdx.x - off];
        __syncthreads();
        if ((int)threadIdx.x >= off) s[threadIdx.x] += t;
        __syncthreads();
    }
    int run = base + s[threadIdx.x] - sum;  // exclusive prefix for this thread
#pragma unroll
    for (int j = 0; j < 4; ++j) {
        int i = i0 + j;
        if (i < N) {
            rowptr[i] = run;
            cursor[i] = run;
            dinv[i]   = rsqrtf((float)v[j] + 1.0f);  // +1 self-loop
            run += v[j];
        }
    }
}

// per-bucket CSR scatter: cursor window 4KB, col window ~64KB (cache-hot)
__global__ __launch_bounds__(THREADS) void csr_scatter_kernel(
    const int2* __restrict__ ePair, const int* __restrict__ bucketOff,
    int* __restrict__ cursor, int* __restrict__ col) {
    const int b    = blockIdx.x >> 2;
    const int part = blockIdx.x & 3;
    const int off = bucketOff[b];
    const int len = bucketOff[b + 1] - off;
    const int lo  = off + (int)(((long long)len * part) >> 2);
    const int hi  = off + (int)(((long long)len * (part + 1)) >> 2);
    for (int e = lo + threadIdx.x; e < hi; e += THREADS) {
        int2 p = ePair[e];
        int pos = atomicAdd(&cursor[p.x], 1);
        col[pos] = p.y;
    }
}

// ---- Aggregation F=64: wave per row, 4 edges/iter, float4 per lane --------

template <bool ACT>
__global__ __launch_bounds__(THREADS) void agg64_kernel(
    const float* __restrict__ h, const int* __restrict__ rowptr,
    const int* __restrict__ col, const float* __restrict__ dinv,
    const float* __restrict__ bias, float* __restrict__ out, int N) {
    const int lane = threadIdx.x & 63;
    const int r = blockIdx.x * 4 + (threadIdx.x >> 6);
    if (r >= N) return;
    const int quad = lane >> 4;   // which of 4 concurrent edges
    const int sub  = lane & 15;   // feature group (4 floats)
    const float4* __restrict__ h4 = (const float4*)h;
    const float dr = dinv[r];
    const int start = rowptr[r];
    const int end   = rowptr[r + 1];

    float4 acc = make_float4(0.f, 0.f, 0.f, 0.f);
    if (quad == 0) {  // self-loop term dr*h[r]
        float4 hv = h4[(size_t)r * 16 + sub];
        acc.x = dr * hv.x; acc.y = dr * hv.y;
        acc.z = dr * hv.z; acc.w = dr * hv.w;
    }

    for (int b = start; b < end; b += 64) {
        int m = end - b; if (m > 64) m = 64;
        int c = 0; float w = 0.0f;
        if (lane < m) { c = col[b + lane]; w = dinv[c]; }
#pragma unroll 2
        for (int j = 0; j < m; j += 4) {
            int   cj = __shfl(c, j + quad);
            float wj = __shfl(w, j + quad);
            float4 hv = h4[(size_t)cj * 16 + sub];
            acc.x += wj * hv.x; acc.y += wj * hv.y;
            acc.z += wj * hv.z; acc.w += wj * hv.w;
        }
    }

#pragma unroll
    for (int off = 32; off >= 16; off >>= 1) {
        acc.x += __shfl_xor(acc.x, off);
        acc.y += __shfl_xor(acc.y, off);
        acc.z += __shfl_xor(acc.z, off);
        acc.w += __shfl_xor(acc.w, off);
    }

    if (quad == 0) {
        float4 res;
        res.x = acc.x * dr; res.y = acc.y * dr;
        res.z = acc.z * dr; res.w = acc.w * dr;
        if constexpr (ACT) {
            float4 bv = ((const float4*)bias)[sub];
            res.x = celu1(res.x + bv.x);
            res.y = celu1(res.y + bv.y);
            res.z = celu1(res.z + bv.z);
            res.w = celu1(res.w + bv.w);
        }
        ((float4*)out)[(size_t)r * 16 + sub] = res;
    }
}

// ---- Aggregation F=128: wave per row, 2 edges/iter, float4 per lane -------

__global__ __launch_bounds__(THREADS) void agg128_kernel(
    const float* __restrict__ h, const int* __restrict__ rowptr,
    const int* __restrict__ col, const float* __restrict__ dinv,
    float* __restrict__ out, int N) {
    const int lane = threadIdx.x & 63;
    const int r = blockIdx.x * 4 + (threadIdx.x >> 6);
    if (r >= N) return;
    const int half = lane >> 5;   // which of 2 concurrent edges
    const int sub  = lane & 31;   // feature group (4 floats)
    const float4* __restrict__ h4 = (const float4*)h;
    const float dr = dinv[r];
    const int start = rowptr[r];
    const int end   = rowptr[r + 1];

    float4 acc = make_float4(0.f, 0.f, 0.f, 0.f);
    if (half == 0) {  // self-loop
        float4 hv = h4[(size_t)r * 32 + sub];
        acc.x = dr * hv.x; acc.y = dr * hv.y;
        acc.z = dr * hv.z; acc.w = dr * hv.w;
    }

    for (int b = start; b < end; b += 64) {
        int m = end - b; if (m > 64) m = 64;
        int c = 0; float w = 0.0f;
        if (lane < m) { c = col[b + lane]; w = dinv[c]; }
#pragma unroll 2
        for (int j = 0; j < m; j += 2) {
            int   cj = __shfl(c, j + half);
            float wj = __shfl(w, j + half);
            float4 hv = h4[(size_t)cj * 32 + sub];
            acc.x += wj * hv.x; acc.y += wj * hv.y;
            acc.z += wj * hv.z; acc.w += wj * hv.w;
        }
    }

    acc.x += __shfl_xor(acc.x, 32);
    acc.y += __shfl_xor(acc.y, 32);
    acc.z += __shfl_xor(acc.z, 32);
    acc.w += __shfl_xor(acc.w, 32);

    if (half == 0) {
        float4 res;
        res.x = acc.x * dr; res.y = acc.y * dr;
        res.z = acc.z * dr; res.w = acc.w * dr;
        ((float4*)out)[(size_t)r * 32 + sub] = res;
    }
}

// ---- Dense transform: out[N,F] = act(X[N,K] @ W[K,F] + b) -----------------

template <int K, int F, bool ACT>
__global__ __launch_bounds__(THREADS) void gemm_kernel(
    const float* __restrict__ X, const float* __restrict__ W,
    const float* __restrict__ bias, float* __restrict__ out, int N) {
    constexpr int ROWS = 32;
    constexpr int KT   = (K > 64) ? 64 : K;
    constexpr int NF4  = F / 4;
    constexpr int G    = THREADS / NF4;
    constexpr int RPT  = ROWS / G;
    __shared__ float Ws[KT * F];
    __shared__ float Xs[ROWS * K];

    const int tid  = threadIdx.x;
    const int row0 = blockIdx.x * ROWS;
    if (row0 >= N) return;

    const float4* Xg = (const float4*)(X + (size_t)row0 * K);
    for (int i = tid; i < ROWS * K / 4; i += THREADS)
        ((float4*)Xs)[i] = Xg[i];

    const int fg = tid % NF4;
    const int rg = tid / NF4;
    float4 acc[RPT];
#pragma unroll
    for (int j = 0; j < RPT; ++j) acc[j] = make_float4(0.f, 0.f, 0.f, 0.f);

    for (int kt = 0; kt < K; kt += KT) {
        __syncthreads();
        const float4* Wg = (const float4*)(W + (size_t)kt * F);
        for (int i = tid; i < KT * F / 4; i += THREADS)
            ((float4*)Ws)[i] = Wg[i];
        __syncthreads();
#pragma unroll 4
        for (int k = 0; k < KT; k += 4) {
            float4 xv[RPT];
#pragma unroll
            for (int j = 0; j < RPT; ++j)
                xv[j] = *(const float4*)&Xs[(rg + j * G) * K + kt + k];
#pragma unroll
            for (int kk = 0; kk < 4; ++kk) {
                float4 wv = *(const float4*)&Ws[(k + kk) * F + fg * 4];
#pragma unroll
                for (int j = 0; j < RPT; ++j) {
                    float xs = ((const float*)&xv[j])[kk];
                    acc[j].x += xs * wv.x;
                    acc[j].y += xs * wv.y;
                    acc[j].z += xs * wv.z;
                    acc[j].w += xs * wv.w;
                }
            }
        }
    }

#pragma unroll
    for (int j = 0; j < RPT; ++j) {
        float4 v = acc[j];
        if constexpr (ACT) {
            float4 bv = ((const float4*)bias)[fg];
            v.x = celu1(v.x + bv.x);
            v.y = celu1(v.y + bv.y);
            v.z = celu1(v.z + bv.z);
            v.w = celu1(v.w + bv.w);
        }
        int r = row0 + rg + j * G;
        *(float4*)&out[(size_t)r * F + fg * 4] = v;
    }
}

// ---------------------------------------------------------------------------

extern "C" void kernel_launch(void* const* d_in, const int* in_sizes, int n_in,
                              void* d_out, int out_size, void* d_ws, size_t ws_size,
                              hipStream_t stream) {
    const float* x  = (const float*)d_in[0];
    const int*   ei = (const int*)d_in[1];
    const float* W1 = (const float*)d_in[2];
    const float* b1 = (const float*)d_in[3];
    const float* W2 = (const float*)d_in[4];
    const float* b2 = (const float*)d_in[5];
    const float* W3 = (const float*)d_in[6];
    const float* b3 = (const float*)d_in[7];
    float* out = (float*)d_out;

    const int N = in_sizes[0] / 64;   // 100000
    const int E = in_sizes[1] / 2;    // 1600000
    const int* src = ei;
    const int* dst = ei + E;
    const int NBUCK = (N + (1 << BSHIFT) - 1) >> BSHIFT;  // 98

    // workspace carve (all 256B-aligned)
    char* p = (char*)d_ws;
    auto carve = [&](size_t bytes) {
        void* q = p;
        p += (bytes + 255) & ~(size_t)255;
        return q;
    };
    int*   cnt       = (int*)carve((size_t)N * sizeof(int));
    int*   rowptr    = (int*)carve((size_t)(N + 1) * sizeof(int));
    int*   cursor    = (int*)carve((size_t)N * sizeof(int));
    int*   col       = (int*)carve((size_t)E * sizeof(int));
    float* dinv      = (float*)carve((size_t)N * sizeof(float));
    int*   partials  = (int*)carve(1024 * sizeof(int));
    int*   bucketCnt = (int*)carve(NBUCK_MAX * sizeof(int));
    int*   bucketOff = (int*)carve((NBUCK_MAX + 1) * sizeof(int));
    int*   bucketCur = (int*)carve(NBUCK_MAX * sizeof(int));
    float* B1        = (float*)carve((size_t)N * 128 * sizeof(float));
    float* B2        = (float*)carve((size_t)N * 128 * sizeof(float));
    int2*  ePair     = (int2*)B1;  // 12.8MB, consumed before layer-1 agg writes B1

    const int NB = (N + 1023) / 1024;
    const int AB = (N + 3) / 4;
    const int GB = (N + 31) / 32;
    const int SB = (E + CHUNK - 1) / CHUNK;

    // --- CSR build (bucketed counting sort) ---
    hipMemsetAsync(bucketCnt, 0, NBUCK_MAX * sizeof(int), stream);
    hipMemsetAsync(cnt, 0, (size_t)N * sizeof(int), stream);
    bucket_hist_kernel<<<512, THREADS, 0, stream>>>(dst, bucketCnt, E, NBUCK);
    bucket_scan_kernel<<<1, 64, 0, stream>>>(bucketCnt, bucketOff, bucketCur, NBUCK, E);
    bucket_scatter_kernel<<<SB, THREADS, 0, stream>>>(src, dst, bucketCur, ePair, E);
    node_hist_kernel<<<NBUCK * 4, THREADS, 0, stream>>>(ePair, bucketOff, cnt, N);
    scanA_kernel<<<NB, THREADS, 0, stream>>>(cnt, partials, N);
    scanB_kernel<<<1, 64, 0, stream>>>(partials, rowptr, NB, N);
    scanC_kernel<<<NB, THREADS, 0, stream>>>(cnt, partials, rowptr, cursor, dinv, N);
    csr_scatter_kernel<<<NBUCK * 4, THREADS, 0, stream>>>(ePair, bucketOff, cursor, col);

    // --- Layer 1: a1 = celu(Agg(x) @ W1 + b1) ---
    agg64_kernel<false><<<AB, THREADS, 0, stream>>>(x, rowptr, col, dinv, nullptr, B1, N);
    gemm_kernel<64, 128, true><<<GB, THREADS, 0, stream>>>(B1, W1, b1, B2, N);

    // --- Layer 2: a2 = celu(Agg(a1) @ W2 + b2) ---
    agg128_kernel<<<AB, THREADS, 0, stream>>>(B2, rowptr, col, dinv, B1, N);
    gemm_kernel<128, 128, true><<<GB, THREADS, 0, stream>>>(B1, W2, b2, B2, N);

    // --- Layer 3: out = celu(Agg(a2 @ W3) + b3) ---
    gemm_kernel<128, 64, false><<<GB, THREADS, 0, stream>>>(B2, W3, nullptr, B1, N);
    agg64_kernel<true><<<AB, THREADS, 0, stream>>>(B1, rowptr, col, dinv, b3, out, N);
}

// Round 4
// 577.567 us; speedup vs baseline: 1.3546x; 1.1300x over previous
//
#include <hip/hip_runtime.h>
#include <hip/hip_fp16.h>
#include <math.h>

// ---------------------------------------------------------------------------
// 3-layer GCN: h = celu(Agg(x)@W1+b1); h = celu(Agg(h)@W2+b2); out = celu(Agg(h@W3)+b3)
// Agg(r) = dinv[r] * ( h[r]*dinv[r] + sum_{s in N(s)} dinv[s]*h[s] )
// R2: locality-bucketed CSR build (dst>>10), all random accesses in hot windows.
// R3: fp16 storage for all gathered feature matrices (fp32 accumulate) —
//     halves gather traffic (the R2 bottleneck: agg128 @123us, 416MB fetch),
//     and doubles edge-parallelism per wave (16B/lane rows).
// ---------------------------------------------------------------------------

#define THREADS 256
#define BSHIFT 10              // nodes per bucket = 1024
#define NBUCK_MAX 128
#define EPT 16                 // edges per thread in bucket_scatter
#define CHUNK (THREADS * EPT)  // 4096 edges per block

__device__ __forceinline__ float celu1(float v) {
    return v > 0.0f ? v : expm1f(v);
}

__device__ __forceinline__ void acc8(float* acc, float w, uint4 u) {
    const __half2* h2 = (const __half2*)&u;
    float2 f;
    f = __half22float2(h2[0]); acc[0] += w * f.x; acc[1] += w * f.y;
    f = __half22float2(h2[1]); acc[2] += w * f.x; acc[3] += w * f.y;
    f = __half22float2(h2[2]); acc[4] += w * f.x; acc[5] += w * f.y;
    f = __half22float2(h2[3]); acc[6] += w * f.x; acc[7] += w * f.y;
}

// ---- fp32 -> fp16 convert (8 elems/thread) --------------------------------

__global__ __launch_bounds__(THREADS) void f2h_kernel(
    const float* __restrict__ in, __half* __restrict__ out, int n8) {
    int i = blockIdx.x * THREADS + threadIdx.x;
    if (i < n8) {
        float4 a = ((const float4*)in)[i * 2];
        float4 b = ((const float4*)in)[i * 2 + 1];
        __half2 h[4] = {__floats2half2_rn(a.x, a.y), __floats2half2_rn(a.z, a.w),
                        __floats2half2_rn(b.x, b.y), __floats2half2_rn(b.z, b.w)};
        ((uint4*)out)[i] = *(uint4*)h;
    }
}

// ---- CSR build: bucketed counting sort ------------------------------------

__global__ __launch_bounds__(THREADS) void bucket_hist_kernel(
    const int* __restrict__ dst, int* __restrict__ bucketCnt, int E, int NBUCK) {
    __shared__ int lcnt[NBUCK_MAX];
    if (threadIdx.x < NBUCK_MAX) lcnt[threadIdx.x] = 0;
    __syncthreads();
    for (int e = blockIdx.x * THREADS + threadIdx.x; e < E; e += gridDim.x * THREADS)
        atomicAdd(&lcnt[dst[e] >> BSHIFT], 1);
    __syncthreads();
    if (threadIdx.x < NBUCK && lcnt[threadIdx.x])
        atomicAdd(&bucketCnt[threadIdx.x], lcnt[threadIdx.x]);
}

__global__ void bucket_scan_kernel(const int* __restrict__ bucketCnt,
                                   int* __restrict__ bucketOff,
                                   int* __restrict__ bucketCur, int NBUCK, int E) {
    if (threadIdx.x == 0) {
        int run = 0;
        for (int b = 0; b < NBUCK; ++b) {
            bucketOff[b] = run;
            bucketCur[b] = run;
            run += bucketCnt[b];
        }
        bucketOff[NBUCK] = run;  // == E
    }
}

__global__ __launch_bounds__(THREADS) void bucket_scatter_kernel(
    const int* __restrict__ src, const int* __restrict__ dst,
    int* __restrict__ bucketCur, int2* __restrict__ ePair, int E) {
    __shared__ int lcnt[NBUCK_MAX];
    __shared__ int lbase[NBUCK_MAX];
    if (threadIdx.x < NBUCK_MAX) lcnt[threadIdx.x] = 0;
    __syncthreads();
    const int base = blockIdx.x * CHUNK;
    int bk[EPT], rk[EPT], dd[EPT], ss[EPT];
#pragma unroll
    for (int i = 0; i < EPT; ++i) {
        int e = base + i * THREADS + threadIdx.x;
        if (e < E) {
            dd[i] = dst[e];
            ss[i] = src[e];
            bk[i] = dd[i] >> BSHIFT;
            rk[i] = atomicAdd(&lcnt[bk[i]], 1);
        } else {
            bk[i] = -1;
        }
    }
    __syncthreads();
    if (threadIdx.x < NBUCK_MAX && lcnt[threadIdx.x])
        lbase[threadIdx.x] = atomicAdd(&bucketCur[threadIdx.x], lcnt[threadIdx.x]);
    __syncthreads();
#pragma unroll
    for (int i = 0; i < EPT; ++i) {
        if (bk[i] >= 0) {
            int p = lbase[bk[i]] + rk[i];
            ePair[p] = make_int2(dd[i], ss[i]);
        }
    }
}

// per-bucket node histogram via LDS counters
__global__ __launch_bounds__(THREADS) void node_hist_kernel(
    const int2* __restrict__ ePair, const int* __restrict__ bucketOff,
    int* __restrict__ cnt, int N) {
    __shared__ int hcnt[1 << BSHIFT];
    const int b    = blockIdx.x >> 2;
    const int part = blockIdx.x & 3;
    for (int i = threadIdx.x; i < (1 << BSHIFT); i += THREADS) hcnt[i] = 0;
    __syncthreads();
    const int off = bucketOff[b];
    const int len = bucketOff[b + 1] - off;
    const int lo  = off + (int)(((long long)len * part) >> 2);
    const int hi  = off + (int)(((long long)len * (part + 1)) >> 2);
    for (int e = lo + threadIdx.x; e < hi; e += THREADS)
        atomicAdd(&hcnt[ePair[e].x & ((1 << BSHIFT) - 1)], 1);
    __syncthreads();
    const int node0 = b << BSHIFT;
    for (int i = threadIdx.x; i < (1 << BSHIFT); i += THREADS) {
        int node = node0 + i;
        if (node < N && hcnt[i]) atomicAdd(&cnt[node], hcnt[i]);
    }
}

__global__ __launch_bounds__(THREADS) void scanA_kernel(
    const int* __restrict__ cnt, int* __restrict__ partials, int N) {
    __shared__ int s[THREADS];
    int i0 = blockIdx.x * 1024 + threadIdx.x * 4;
    int sum = 0;
#pragma unroll
    for (int j = 0; j < 4; ++j) {
        int i = i0 + j;
        if (i < N) sum += cnt[i];
    }
    s[threadIdx.x] = sum;
    __syncthreads();
    for (int off = THREADS / 2; off > 0; off >>= 1) {
        if (threadIdx.x < off) s[threadIdx.x] += s[threadIdx.x + off];
        __syncthreads();
    }
    if (threadIdx.x == 0) partials[blockIdx.x] = s[0];
}

__global__ void scanB_kernel(int* __restrict__ partials, int* __restrict__ rowptr,
                             int NB, int N) {
    if (threadIdx.x == 0 && blockIdx.x == 0) {
        int run = 0;
        for (int i = 0; i < NB; ++i) {
            int t = partials[i];
            partials[i] = run;
            run += t;
        }
        rowptr[N] = run;  // == E
    }
}

__global__ __launch_bounds__(THREADS) void scanC_kernel(
    const int* __restrict__ cnt, const int* __restrict__ partials,
    int* __restrict__ rowptr, int* __restrict__ cursor,
    float* __restrict__ dinv, int N) {
    __shared__ int s[THREADS];
    int base = partials[blockIdx.x];
    int i0 = blockIdx.x * 1024 + threadIdx.x * 4;
    int v[4];
    int sum = 0;
#pragma unroll
    for (int j = 0; j < 4; ++j) {
        int i = i0 + j;
        v[j] = (i < N) ? cnt[i] : 0;
        sum += v[j];
    }
    s[threadIdx.x] = sum;
    __syncthreads();
    for (int off = 1; off < THREADS; off <<= 1) {
        int t = 0;
        if ((int)threadIdx.x >= off) t = s[threadIdx.x - off];
        __syncthreads();
        if ((int)threadIdx.x >= off) s[threadIdx.x] += t;
        __syncthreads();
    }
    int run = base + s[threadIdx.x] - sum;
#pragma unroll
    for (int j = 0; j < 4; ++j) {
        int i = i0 + j;
        if (i < N) {
            rowptr[i] = run;
            cursor[i] = run;
            dinv[i]   = rsqrtf((float)v[j] + 1.0f);  // +1 self-loop
            run += v[j];
        }
    }
}

__global__ __launch_bounds__(THREADS) void csr_scatter_kernel(
    const int2* __restrict__ ePair, const int* __restrict__ bucketOff,
    int* __restrict__ cursor, int* __restrict__ col) {
    const int b    = blockIdx.x >> 2;
    const int part = blockIdx.x & 3;
    const int off = bucketOff[b];
    const int len = bucketOff[b + 1] - off;
    const int lo  = off + (int)(((long long)len * part) >> 2);
    const int hi  = off + (int)(((long long)len * (part + 1)) >> 2);
    for (int e = lo + threadIdx.x; e < hi; e += THREADS) {
        int2 p = ePair[e];
        int pos = atomicAdd(&cursor[p.x], 1);
        col[pos] = p.y;
    }
}

// ---- Aggregation F=64 (fp16 in): wave per row, 8 edges/iter ---------------
// 8 lanes per edge, 16B (8 halves) per lane. fp32 accumulate.

template <bool ACT>
__global__ __launch_bounds__(THREADS) void agg64h_kernel(
    const __half* __restrict__ h, const int* __restrict__ rowptr,
    const int* __restrict__ col, const float* __restrict__ dinv,
    const float* __restrict__ bias, float* __restrict__ out, int N) {
    const int lane = threadIdx.x & 63;
    const int r = blockIdx.x * 4 + (threadIdx.x >> 6);
    if (r >= N) return;
    const int oct = lane >> 3;   // which of 8 concurrent edges
    const int sub = lane & 7;    // 8-half group
    const uint4* __restrict__ h4 = (const uint4*)h;  // 8 uint4 per row
    const float dr = dinv[r];
    const int start = rowptr[r];
    const int end   = rowptr[r + 1];

    float acc[8] = {0.f, 0.f, 0.f, 0.f, 0.f, 0.f, 0.f, 0.f};
    if (oct == 0)  // self-loop term dr*h[r]
        acc8(acc, dr, h4[(size_t)r * 8 + sub]);

    for (int b = start; b < end; b += 64) {
        int m = end - b; if (m > 64) m = 64;
        int c = 0; float w = 0.0f;
        if (lane < m) { c = col[b + lane]; w = dinv[c]; }
#pragma unroll 2
        for (int j = 0; j < m; j += 8) {
            int   cj = __shfl(c, j + oct);
            float wj = __shfl(w, j + oct);
            acc8(acc, wj, h4[(size_t)cj * 8 + sub]);
        }
    }

#pragma unroll
    for (int off = 32; off >= 8; off >>= 1)
#pragma unroll
        for (int k = 0; k < 8; ++k)
            acc[k] += __shfl_xor(acc[k], off);

    if (oct == 0) {
        float res[8];
#pragma unroll
        for (int k = 0; k < 8; ++k) res[k] = acc[k] * dr;
        if constexpr (ACT) {
            const float* bp = bias + sub * 8;
#pragma unroll
            for (int k = 0; k < 8; ++k) res[k] = celu1(res[k] + bp[k]);
        }
        float4* o4 = (float4*)(out + (size_t)r * 64 + sub * 8);
        o4[0] = make_float4(res[0], res[1], res[2], res[3]);
        o4[1] = make_float4(res[4], res[5], res[6], res[7]);
    }
}

// ---- Aggregation F=128 (fp16 in): wave per row, 4 edges/iter --------------

__global__ __launch_bounds__(THREADS) void agg128h_kernel(
    const __half* __restrict__ h, const int* __restrict__ rowptr,
    const int* __restrict__ col, const float* __restrict__ dinv,
    float* __restrict__ out, int N) {
    const int lane = threadIdx.x & 63;
    const int r = blockIdx.x * 4 + (threadIdx.x >> 6);
    if (r >= N) return;
    const int quad = lane >> 4;  // which of 4 concurrent edges
    const int sub  = lane & 15;  // 8-half group
    const uint4* __restrict__ h4 = (const uint4*)h;  // 16 uint4 per row
    const float dr = dinv[r];
    const int start = rowptr[r];
    const int end   = rowptr[r + 1];

    float acc[8] = {0.f, 0.f, 0.f, 0.f, 0.f, 0.f, 0.f, 0.f};
    if (quad == 0)  // self-loop
        acc8(acc, dr, h4[(size_t)r * 16 + sub]);

    for (int b = start; b < end; b += 64) {
        int m = end - b; if (m > 64) m = 64;
        int c = 0; float w = 0.0f;
        if (lane < m) { c = col[b + lane]; w = dinv[c]; }
#pragma unroll 2
        for (int j = 0; j < m; j += 4) {
            int   cj = __shfl(c, j + quad);
            float wj = __shfl(w, j + quad);
            acc8(acc, wj, h4[(size_t)cj * 16 + sub]);
        }
    }

#pragma unroll
    for (int off = 32; off >= 16; off >>= 1)
#pragma unroll
        for (int k = 0; k < 8; ++k)
            acc[k] += __shfl_xor(acc[k], off);

    if (quad == 0) {
        float4* o4 = (float4*)(out + (size_t)r * 128 + sub * 8);
        o4[0] = make_float4(acc[0] * dr, acc[1] * dr, acc[2] * dr, acc[3] * dr);
        o4[1] = make_float4(acc[4] * dr, acc[5] * dr, acc[6] * dr, acc[7] * dr);
    }
}

// ---- Dense transform: out[N,F] = act(X[N,K] @ W[K,F] + b) -----------------
// HALF_OUT: write fp16 (feeds the next gather).

template <int K, int F, bool ACT, bool HALF_OUT>
__global__ __launch_bounds__(THREADS) void gemm_kernel(
    const float* __restrict__ X, const float* __restrict__ W,
    const float* __restrict__ bias, void* __restrict__ outv, int N) {
    constexpr int ROWS = 32;
    constexpr int KT   = (K > 64) ? 64 : K;
    constexpr int NF4  = F / 4;
    constexpr int G    = THREADS / NF4;
    constexpr int RPT  = ROWS / G;
    __shared__ float Ws[KT * F];
    __shared__ float Xs[ROWS * K];

    const int tid  = threadIdx.x;
    const int row0 = blockIdx.x * ROWS;
    if (row0 >= N) return;

    const float4* Xg = (const float4*)(X + (size_t)row0 * K);
    for (int i = tid; i < ROWS * K / 4; i += THREADS)
        ((float4*)Xs)[i] = Xg[i];

    const int fg = tid % NF4;
    const int rg = tid / NF4;
    float4 acc[RPT];
#pragma unroll
    for (int j = 0; j < RPT; ++j) acc[j] = make_float4(0.f, 0.f, 0.f, 0.f);

    for (int kt = 0; kt < K; kt += KT) {
        __syncthreads();
        const float4* Wg = (const float4*)(W + (size_t)kt * F);
        for (int i = tid; i < KT * F / 4; i += THREADS)
            ((float4*)Ws)[i] = Wg[i];
        __syncthreads();
#pragma unroll 4
        for (int k = 0; k < KT; k += 4) {
            float4 xv[RPT];
#pragma unroll
            for (int j = 0; j < RPT; ++j)
                xv[j] = *(const float4*)&Xs[(rg + j * G) * K + kt + k];
#pragma unroll
            for (int kk = 0; kk < 4; ++kk) {
                float4 wv = *(const float4*)&Ws[(k + kk) * F + fg * 4];
#pragma unroll
                for (int j = 0; j < RPT; ++j) {
                    float xs = ((const float*)&xv[j])[kk];
                    acc[j].x += xs * wv.x;
                    acc[j].y += xs * wv.y;
                    acc[j].z += xs * wv.z;
                    acc[j].w += xs * wv.w;
                }
            }
        }
    }

#pragma unroll
    for (int j = 0; j < RPT; ++j) {
        float4 v = acc[j];
        if constexpr (ACT) {
            float4 bv = ((const float4*)bias)[fg];
            v.x = celu1(v.x + bv.x);
            v.y = celu1(v.y + bv.y);
            v.z = celu1(v.z + bv.z);
            v.w = celu1(v.w + bv.w);
        }
        int r = row0 + rg + j * G;
        if constexpr (HALF_OUT) {
            __half2* o2 = (__half2*)((__half*)outv + (size_t)r * F + fg * 4);
            o2[0] = __floats2half2_rn(v.x, v.y);
            o2[1] = __floats2half2_rn(v.z, v.w);
        } else {
            *(float4*)&((float*)outv)[(size_t)r * F + fg * 4] = v;
        }
    }
}

// ---------------------------------------------------------------------------

extern "C" void kernel_launch(void* const* d_in, const int* in_sizes, int n_in,
                              void* d_out, int out_size, void* d_ws, size_t ws_size,
                              hipStream_t stream) {
    const float* x  = (const float*)d_in[0];
    const int*   ei = (const int*)d_in[1];
    const float* W1 = (const float*)d_in[2];
    const float* b1 = (const float*)d_in[3];
    const float* W2 = (const float*)d_in[4];
    const float* b2 = (const float*)d_in[5];
    const float* W3 = (const float*)d_in[6];
    const float* b3 = (const float*)d_in[7];
    float* out = (float*)d_out;

    const int N = in_sizes[0] / 64;   // 100000
    const int E = in_sizes[1] / 2;    // 1600000
    const int* src = ei;
    const int* dst = ei + E;
    const int NBUCK = (N + (1 << BSHIFT) - 1) >> BSHIFT;  // 98

    char* p = (char*)d_ws;
    auto carve = [&](size_t bytes) {
        void* q = p;
        p += (bytes + 255) & ~(size_t)255;
        return q;
    };
    int*   cnt       = (int*)carve((size_t)N * sizeof(int));
    int*   rowptr    = (int*)carve((size_t)(N + 1) * sizeof(int));
    int*   cursor    = (int*)carve((size_t)N * sizeof(int));
    int*   col       = (int*)carve((size_t)E * sizeof(int));
    float* dinv      = (float*)carve((size_t)N * sizeof(float));
    int*   partials  = (int*)carve(1024 * sizeof(int));
    int*   bucketCnt = (int*)carve(NBUCK_MAX * sizeof(int));
    int*   bucketOff = (int*)carve((NBUCK_MAX + 1) * sizeof(int));
    int*   bucketCur = (int*)carve(NBUCK_MAX * sizeof(int));
    __half* xh       = (__half*)carve((size_t)N * 64 * sizeof(__half));
    float* B1        = (float*)carve((size_t)N * 128 * sizeof(float));
    float* B2        = (float*)carve((size_t)N * 128 * sizeof(float));
    int2*  ePair     = (int2*)B1;      // consumed before layer-1 agg writes B1
    __half* B2h      = (__half*)B2;    // gemm1 fp16 out (consumed by agg128h before gemm2 writes B2)
    __half* B1h      = (__half*)B1;    // gemm3 fp16 out (B1 free after gemm2 reads it)

    const int NB = (N + 1023) / 1024;
    const int AB = (N + 3) / 4;
    const int GB = (N + 31) / 32;
    const int SB = (E + CHUNK - 1) / CHUNK;
    const int FB = (N * 8 + THREADS - 1) / THREADS;  // f2h blocks (8 elems/thread)

    // --- CSR build (bucketed counting sort) + x->fp16 ---
    hipMemsetAsync(bucketCnt, 0, NBUCK_MAX * sizeof(int), stream);
    hipMemsetAsync(cnt, 0, (size_t)N * sizeof(int), stream);
    f2h_kernel<<<FB, THREADS, 0, stream>>>(x, xh, N * 8);
    bucket_hist_kernel<<<512, THREADS, 0, stream>>>(dst, bucketCnt, E, NBUCK);
    bucket_scan_kernel<<<1, 64, 0, stream>>>(bucketCnt, bucketOff, bucketCur, NBUCK, E);
    bucket_scatter_kernel<<<SB, THREADS, 0, stream>>>(src, dst, bucketCur, ePair, E);
    node_hist_kernel<<<NBUCK * 4, THREADS, 0, stream>>>(ePair, bucketOff, cnt, N);
    scanA_kernel<<<NB, THREADS, 0, stream>>>(cnt, partials, N);
    scanB_kernel<<<1, 64, 0, stream>>>(partials, rowptr, NB, N);
    scanC_kernel<<<NB, THREADS, 0, stream>>>(cnt, partials, rowptr, cursor, dinv, N);
    csr_scatter_kernel<<<NBUCK * 4, THREADS, 0, stream>>>(ePair, bucketOff, cursor, col);

    // --- Layer 1: a1 = celu(Agg(x) @ W1 + b1), a1 in fp16 (B2h) ---
    agg64h_kernel<false><<<AB, THREADS, 0, stream>>>(xh, rowptr, col, dinv, nullptr, B1, N);
    gemm_kernel<64, 128, true, true><<<GB, THREADS, 0, stream>>>(B1, W1, b1, B2h, N);

    // --- Layer 2: a2 = celu(Agg(a1) @ W2 + b2), fp32 (B2) ---
    agg128h_kernel<<<AB, THREADS, 0, stream>>>(B2h, rowptr, col, dinv, B1, N);
    gemm_kernel<128, 128, true, false><<<GB, THREADS, 0, stream>>>(B1, W2, b2, B2, N);

    // --- Layer 3: out = celu(Agg(a2 @ W3) + b3) ---
    gemm_kernel<128, 64, false, true><<<GB, THREADS, 0, stream>>>(B2, W3, nullptr, B1h, N);
    agg64h_kernel<true><<<AB, THREADS, 0, stream>>>(B1h, rowptr, col, dinv, b3, out, N);
}

// Round 5
// 468.318 us; speedup vs baseline: 1.6706x; 1.2333x over previous
//
#include <hip/hip_runtime.h>
#include <hip/hip_fp16.h>
#include <math.h>

// ---------------------------------------------------------------------------
// 3-layer GCN: h = celu(Agg(x)@W1+b1); h = celu(Agg(h)@W2+b2); out = celu(Agg(h@W3)+b3)
// Agg(r) = dinv[r] * ( h[r]*dinv[r] + sum_{s in N(r)} dinv[s]*h[s] )
// R2: locality-bucketed CSR build. R3: fp16 gather storage (fp32 accumulate).
// R4: kill per-edge device-scope atomics (R4 profile: csr_scatter 120us,
//     WRITE 95MB ~= E*64B fabric transactions). One block per 256-node
//     bucket builds hist+scan+scatter with LDS-only atomics; packed 1-int
//     edge records; parallel bucket scan. node_hist/scanA/B/C/csr_scatter
//     are deleted.
// ---------------------------------------------------------------------------

#define THREADS 256
#define SCANT 512
#define BSHIFT 8               // nodes per bucket = 256
#define BNODES (1 << BSHIFT)
#define NBUCK_MAX 512
#define EPT 16                 // edges per thread in bucket_scatter
#define CHUNK (THREADS * EPT)  // 4096 edges per block

__device__ __forceinline__ float celu1(float v) {
    return v > 0.0f ? v : expm1f(v);
}

__device__ __forceinline__ void acc8(float* acc, float w, uint4 u) {
    const __half2* h2 = (const __half2*)&u;
    float2 f;
    f = __half22float2(h2[0]); acc[0] += w * f.x; acc[1] += w * f.y;
    f = __half22float2(h2[1]); acc[2] += w * f.x; acc[3] += w * f.y;
    f = __half22float2(h2[2]); acc[4] += w * f.x; acc[5] += w * f.y;
    f = __half22float2(h2[3]); acc[6] += w * f.x; acc[7] += w * f.y;
}

// ---- fp32 -> fp16 convert (8 elems/thread) --------------------------------

__global__ __launch_bounds__(THREADS) void f2h_kernel(
    const float* __restrict__ in, __half* __restrict__ out, int n8) {
    int i = blockIdx.x * THREADS + threadIdx.x;
    if (i < n8) {
        float4 a = ((const float4*)in)[i * 2];
        float4 b = ((const float4*)in)[i * 2 + 1];
        __half2 h[4] = {__floats2half2_rn(a.x, a.y), __floats2half2_rn(a.z, a.w),
                        __floats2half2_rn(b.x, b.y), __floats2half2_rn(b.z, b.w)};
        ((uint4*)out)[i] = *(uint4*)h;
    }
}

// ---- CSR build: bucketed counting sort, LDS-atomic only -------------------

__global__ __launch_bounds__(THREADS) void bucket_hist_kernel(
    const int* __restrict__ dst, int* __restrict__ bucketCnt, int E, int NBUCK) {
    __shared__ int lcnt[NBUCK_MAX];
    for (int i = threadIdx.x; i < NBUCK; i += THREADS) lcnt[i] = 0;
    __syncthreads();
    for (int e = blockIdx.x * THREADS + threadIdx.x; e < E; e += gridDim.x * THREADS)
        atomicAdd(&lcnt[dst[e] >> BSHIFT], 1);
    __syncthreads();
    for (int i = threadIdx.x; i < NBUCK; i += THREADS)
        if (lcnt[i]) atomicAdd(&bucketCnt[i], lcnt[i]);
}

// parallel exclusive scan over buckets (one block); also seeds rowptr[N]=E
__global__ __launch_bounds__(SCANT) void bucket_scan_kernel(
    const int* __restrict__ bucketCnt, int* __restrict__ bucketOff,
    int* __restrict__ bucketCur, int* __restrict__ rowptr, int NBUCK, int N) {
    __shared__ int s[SCANT];
    const int tid = threadIdx.x;
    int v = (tid < NBUCK) ? bucketCnt[tid] : 0;
    s[tid] = v;
    __syncthreads();
    for (int off = 1; off < SCANT; off <<= 1) {
        int t = 0;
        if (tid >= off) t = s[tid - off];
        __syncthreads();
        if (tid >= off) s[tid] += t;
        __syncthreads();
    }
    if (tid < NBUCK) {
        int ex = s[tid] - v;
        bucketOff[tid] = ex;
        bucketCur[tid] = ex;
    }
    if (tid == 0) {
        int total = s[SCANT - 1];
        bucketOff[NBUCK] = total;  // == E
        rowptr[N] = total;
    }
}

// packed edge record: (dst & (BNODES-1)) << 20 | src   (valid: N < 2^20)
__global__ __launch_bounds__(THREADS) void bucket_scatter_kernel(
    const int* __restrict__ src, const int* __restrict__ dst,
    int* __restrict__ bucketCur, int* __restrict__ ePack, int E, int NBUCK) {
    __shared__ int lcnt[NBUCK_MAX];
    __shared__ int lbase[NBUCK_MAX];
    for (int i = threadIdx.x; i < NBUCK; i += THREADS) lcnt[i] = 0;
    __syncthreads();
    const int base = blockIdx.x * CHUNK;
    int bk[EPT], rk[EPT], pk[EPT];
#pragma unroll
    for (int i = 0; i < EPT; ++i) {
        int e = base + i * THREADS + threadIdx.x;
        if (e < E) {
            int d = dst[e];
            pk[i] = ((d & (BNODES - 1)) << 20) | src[e];
            bk[i] = d >> BSHIFT;
            rk[i] = atomicAdd(&lcnt[bk[i]], 1);
        } else {
            bk[i] = -1;
        }
    }
    __syncthreads();
    for (int i = threadIdx.x; i < NBUCK; i += THREADS)
        if (lcnt[i]) lbase[i] = atomicAdd(&bucketCur[i], lcnt[i]);
    __syncthreads();
#pragma unroll
    for (int i = 0; i < EPT; ++i) {
        if (bk[i] >= 0) ePack[lbase[bk[i]] + rk[i]] = pk[i];
    }
}

// one block per bucket: LDS hist -> LDS scan -> rowptr/dinv/col, no global atomics
__global__ __launch_bounds__(THREADS) void build_kernel(
    const int* __restrict__ ePack, const int* __restrict__ bucketOff,
    int* __restrict__ rowptr, float* __restrict__ dinv,
    int* __restrict__ col, int N) {
    __shared__ int hist[BNODES];
    __shared__ int scn[BNODES];
    const int tid = threadIdx.x;
    const int b = blockIdx.x;
    const int off = bucketOff[b];
    const int end = bucketOff[b + 1];
    hist[tid] = 0;
    __syncthreads();
    // pass 1: per-node histogram (LDS atomics)
    for (int e = off + tid; e < end; e += THREADS)
        atomicAdd(&hist[((unsigned)ePack[e]) >> 20], 1);
    __syncthreads();
    int deg = hist[tid];
    scn[tid] = deg;
    __syncthreads();
    // inclusive Hillis-Steele scan
    for (int o = 1; o < BNODES; o <<= 1) {
        int t = 0;
        if (tid >= o) t = scn[tid - o];
        __syncthreads();
        if (tid >= o) scn[tid] += t;
        __syncthreads();
    }
    int ex = off + scn[tid] - deg;  // exclusive prefix = CSR start
    const int node = (b << BSHIFT) + tid;
    if (node < N) {
        rowptr[node] = ex;
        dinv[node] = rsqrtf((float)deg + 1.0f);  // +1 self-loop
    }
    scn[tid] = ex;  // becomes the LDS cursor
    __syncthreads();
    // pass 2: scatter (LDS cursor atomics, cache-hot 16KB col window)
    for (int e = off + tid; e < end; e += THREADS) {
        int p = ePack[e];
        int pos = atomicAdd(&scn[((unsigned)p) >> 20], 1);
        col[pos] = p & 0xFFFFF;
    }
}

// ---- Aggregation F=64 (fp16 in): wave per row, 8 edges/iter ---------------

template <bool ACT>
__global__ __launch_bounds__(THREADS) void agg64h_kernel(
    const __half* __restrict__ h, const int* __restrict__ rowptr,
    const int* __restrict__ col, const float* __restrict__ dinv,
    const float* __restrict__ bias, float* __restrict__ out, int N) {
    const int lane = threadIdx.x & 63;
    const int r = blockIdx.x * 4 + (threadIdx.x >> 6);
    if (r >= N) return;
    const int oct = lane >> 3;   // which of 8 concurrent edges
    const int sub = lane & 7;    // 8-half group
    const uint4* __restrict__ h4 = (const uint4*)h;  // 8 uint4 per row
    const float dr = dinv[r];
    const int start = rowptr[r];
    const int end   = rowptr[r + 1];

    float acc[8] = {0.f, 0.f, 0.f, 0.f, 0.f, 0.f, 0.f, 0.f};
    if (oct == 0)  // self-loop term dr*h[r]
        acc8(acc, dr, h4[(size_t)r * 8 + sub]);

    for (int b = start; b < end; b += 64) {
        int m = end - b; if (m > 64) m = 64;
        int c = 0; float w = 0.0f;
        if (lane < m) { c = col[b + lane]; w = dinv[c]; }
#pragma unroll 2
        for (int j = 0; j < m; j += 8) {
            int   cj = __shfl(c, j + oct);
            float wj = __shfl(w, j + oct);
            acc8(acc, wj, h4[(size_t)cj * 8 + sub]);
        }
    }

#pragma unroll
    for (int off = 32; off >= 8; off >>= 1)
#pragma unroll
        for (int k = 0; k < 8; ++k)
            acc[k] += __shfl_xor(acc[k], off);

    if (oct == 0) {
        float res[8];
#pragma unroll
        for (int k = 0; k < 8; ++k) res[k] = acc[k] * dr;
        if constexpr (ACT) {
            const float* bp = bias + sub * 8;
#pragma unroll
            for (int k = 0; k < 8; ++k) res[k] = celu1(res[k] + bp[k]);
        }
        float4* o4 = (float4*)(out + (size_t)r * 64 + sub * 8);
        o4[0] = make_float4(res[0], res[1], res[2], res[3]);
        o4[1] = make_float4(res[4], res[5], res[6], res[7]);
    }
}

// ---- Aggregation F=128 (fp16 in): wave per row, 4 edges/iter --------------

__global__ __launch_bounds__(THREADS) void agg128h_kernel(
    const __half* __restrict__ h, const int* __restrict__ rowptr,
    const int* __restrict__ col, const float* __restrict__ dinv,
    float* __restrict__ out, int N) {
    const int lane = threadIdx.x & 63;
    const int r = blockIdx.x * 4 + (threadIdx.x >> 6);
    if (r >= N) return;
    const int quad = lane >> 4;  // which of 4 concurrent edges
    const int sub  = lane & 15;  // 8-half group
    const uint4* __restrict__ h4 = (const uint4*)h;  // 16 uint4 per row
    const float dr = dinv[r];
    const int start = rowptr[r];
    const int end   = rowptr[r + 1];

    float acc[8] = {0.f, 0.f, 0.f, 0.f, 0.f, 0.f, 0.f, 0.f};
    if (quad == 0)  // self-loop
        acc8(acc, dr, h4[(size_t)r * 16 + sub]);

    for (int b = start; b < end; b += 64) {
        int m = end - b; if (m > 64) m = 64;
        int c = 0; float w = 0.0f;
        if (lane < m) { c = col[b + lane]; w = dinv[c]; }
#pragma unroll 2
        for (int j = 0; j < m; j += 4) {
            int   cj = __shfl(c, j + quad);
            float wj = __shfl(w, j + quad);
            acc8(acc, wj, h4[(size_t)cj * 16 + sub]);
        }
    }

#pragma unroll
    for (int off = 32; off >= 16; off >>= 1)
#pragma unroll
        for (int k = 0; k < 8; ++k)
            acc[k] += __shfl_xor(acc[k], off);

    if (quad == 0) {
        float4* o4 = (float4*)(out + (size_t)r * 128 + sub * 8);
        o4[0] = make_float4(acc[0] * dr, acc[1] * dr, acc[2] * dr, acc[3] * dr);
        o4[1] = make_float4(acc[4] * dr, acc[5] * dr, acc[6] * dr, acc[7] * dr);
    }
}

// ---- Dense transform: out[N,F] = act(X[N,K] @ W[K,F] + b) -----------------

template <int K, int F, bool ACT, bool HALF_OUT>
__global__ __launch_bounds__(THREADS) void gemm_kernel(
    const float* __restrict__ X, const float* __restrict__ W,
    const float* __restrict__ bias, void* __restrict__ outv, int N) {
    constexpr int ROWS = 32;
    constexpr int KT   = (K > 64) ? 64 : K;
    constexpr int NF4  = F / 4;
    constexpr int G    = THREADS / NF4;
    constexpr int RPT  = ROWS / G;
    __shared__ float Ws[KT * F];
    __shared__ float Xs[ROWS * K];

    const int tid  = threadIdx.x;
    const int row0 = blockIdx.x * ROWS;
    if (row0 >= N) return;

    const float4* Xg = (const float4*)(X + (size_t)row0 * K);
    for (int i = tid; i < ROWS * K / 4; i += THREADS)
        ((float4*)Xs)[i] = Xg[i];

    const int fg = tid % NF4;
    const int rg = tid / NF4;
    float4 acc[RPT];
#pragma unroll
    for (int j = 0; j < RPT; ++j) acc[j] = make_float4(0.f, 0.f, 0.f, 0.f);

    for (int kt = 0; kt < K; kt += KT) {
        __syncthreads();
        const float4* Wg = (const float4*)(W + (size_t)kt * F);
        for (int i = tid; i < KT * F / 4; i += THREADS)
            ((float4*)Ws)[i] = Wg[i];
        __syncthreads();
#pragma unroll 4
        for (int k = 0; k < KT; k += 4) {
            float4 xv[RPT];
#pragma unroll
            for (int j = 0; j < RPT; ++j)
                xv[j] = *(const float4*)&Xs[(rg + j * G) * K + kt + k];
#pragma unroll
            for (int kk = 0; kk < 4; ++kk) {
                float4 wv = *(const float4*)&Ws[(k + kk) * F + fg * 4];
#pragma unroll
                for (int j = 0; j < RPT; ++j) {
                    float xs = ((const float*)&xv[j])[kk];
                    acc[j].x += xs * wv.x;
                    acc[j].y += xs * wv.y;
                    acc[j].z += xs * wv.z;
                    acc[j].w += xs * wv.w;
                }
            }
        }
    }

#pragma unroll
    for (int j = 0; j < RPT; ++j) {
        float4 v = acc[j];
        if constexpr (ACT) {
            float4 bv = ((const float4*)bias)[fg];
            v.x = celu1(v.x + bv.x);
            v.y = celu1(v.y + bv.y);
            v.z = celu1(v.z + bv.z);
            v.w = celu1(v.w + bv.w);
        }
        int r = row0 + rg + j * G;
        if constexpr (HALF_OUT) {
            __half2* o2 = (__half2*)((__half*)outv + (size_t)r * F + fg * 4);
            o2[0] = __floats2half2_rn(v.x, v.y);
            o2[1] = __floats2half2_rn(v.z, v.w);
        } else {
            *(float4*)&((float*)outv)[(size_t)r * F + fg * 4] = v;
        }
    }
}

// ---------------------------------------------------------------------------

extern "C" void kernel_launch(void* const* d_in, const int* in_sizes, int n_in,
                              void* d_out, int out_size, void* d_ws, size_t ws_size,
                              hipStream_t stream) {
    const float* x  = (const float*)d_in[0];
    const int*   ei = (const int*)d_in[1];
    const float* W1 = (const float*)d_in[2];
    const float* b1 = (const float*)d_in[3];
    const float* W2 = (const float*)d_in[4];
    const float* b2 = (const float*)d_in[5];
    const float* W3 = (const float*)d_in[6];
    const float* b3 = (const float*)d_in[7];
    float* out = (float*)d_out;

    const int N = in_sizes[0] / 64;   // 100000
    const int E = in_sizes[1] / 2;    // 1600000
    const int* src = ei;
    const int* dst = ei + E;
    const int NBUCK = (N + BNODES - 1) >> BSHIFT;  // 391

    char* p = (char*)d_ws;
    auto carve = [&](size_t bytes) {
        void* q = p;
        p += (bytes + 255) & ~(size_t)255;
        return q;
    };
    int*   rowptr    = (int*)carve((size_t)(N + 1) * sizeof(int));
    int*   col       = (int*)carve((size_t)E * sizeof(int));
    float* dinv      = (float*)carve((size_t)N * sizeof(float));
    int*   bucketCnt = (int*)carve(NBUCK_MAX * sizeof(int));
    int*   bucketOff = (int*)carve((NBUCK_MAX + 1) * sizeof(int));
    int*   bucketCur = (int*)carve(NBUCK_MAX * sizeof(int));
    __half* xh       = (__half*)carve((size_t)N * 64 * sizeof(__half));
    float* B1        = (float*)carve((size_t)N * 128 * sizeof(float));
    float* B2        = (float*)carve((size_t)N * 128 * sizeof(float));
    int*   ePack     = (int*)B1;       // 6.4MB, consumed before agg64h writes B1
    __half* B2h      = (__half*)B2;    // gemm1 fp16 out (consumed before gemm2 writes B2)
    __half* B1h      = (__half*)B1;    // gemm3 fp16 out (B1 free after gemm2 reads it)

    const int AB = (N + 3) / 4;
    const int GB = (N + 31) / 32;
    const int SB = (E + CHUNK - 1) / CHUNK;
    const int FB = (N * 8 + THREADS - 1) / THREADS;

    // --- CSR build (bucketed counting sort, LDS-atomic only) + x->fp16 ---
    hipMemsetAsync(bucketCnt, 0, NBUCK_MAX * sizeof(int), stream);
    f2h_kernel<<<FB, THREADS, 0, stream>>>(x, xh, N * 8);
    bucket_hist_kernel<<<256, THREADS, 0, stream>>>(dst, bucketCnt, E, NBUCK);
    bucket_scan_kernel<<<1, SCANT, 0, stream>>>(bucketCnt, bucketOff, bucketCur, rowptr, NBUCK, N);
    bucket_scatter_kernel<<<SB, THREADS, 0, stream>>>(src, dst, bucketCur, ePack, E, NBUCK);
    build_kernel<<<NBUCK, THREADS, 0, stream>>>(ePack, bucketOff, rowptr, dinv, col, N);

    // --- Layer 1: a1 = celu(Agg(x) @ W1 + b1), a1 in fp16 (B2h) ---
    agg64h_kernel<false><<<AB, THREADS, 0, stream>>>(xh, rowptr, col, dinv, nullptr, B1, N);
    gemm_kernel<64, 128, true, true><<<GB, THREADS, 0, stream>>>(B1, W1, b1, B2h, N);

    // --- Layer 2: a2 = celu(Agg(a1) @ W2 + b2), fp32 (B2) ---
    agg128h_kernel<<<AB, THREADS, 0, stream>>>(B2h, rowptr, col, dinv, B1, N);
    gemm_kernel<128, 128, true, false><<<GB, THREADS, 0, stream>>>(B1, W2, b2, B2, N);

    // --- Layer 3: out = celu(Agg(a2 @ W3) + b3) ---
    gemm_kernel<128, 64, false, true><<<GB, THREADS, 0, stream>>>(B2, W3, nullptr, B1h, N);
    agg64h_kernel<true><<<AB, THREADS, 0, stream>>>(B1h, rowptr, col, dinv, b3, out, N);
}

// Round 6
// 388.992 us; speedup vs baseline: 2.0113x; 1.2039x over previous
//
#include <hip/hip_runtime.h>
#include <hip/hip_fp16.h>
#include <math.h>

// ---------------------------------------------------------------------------
// 3-layer GCN. R2: bucketed CSR build. R3: fp16 gathers. R4: LDS-only CSR.
// R5: MFMA (16x16x32_f16) dense transforms, all inter-kernel buffers fp16.
//   A-frag: A[m=lane&15][k=quad*8+j] (m120-verified). B from Wt[F][K] LDS,
//   B[k=quad*8+j][n=lane&15]. C/D: col=lane&15, row=quad*4+reg (m89/m91).
// ---------------------------------------------------------------------------

#define THREADS 256
#define SCANT 512
#define BSHIFT 8               // nodes per bucket = 256
#define BNODES (1 << BSHIFT)
#define NBUCK_MAX 512
#define EPT 16
#define CHUNK (THREADS * EPT)

typedef _Float16 half8 __attribute__((ext_vector_type(8)));
typedef float floatx4 __attribute__((ext_vector_type(4)));

__device__ __forceinline__ float celu1(float v) {
    return v > 0.0f ? v : expm1f(v);
}

__device__ __forceinline__ void acc8(float* acc, float w, uint4 u) {
    const __half2* h2 = (const __half2*)&u;
    float2 f;
    f = __half22float2(h2[0]); acc[0] += w * f.x; acc[1] += w * f.y;
    f = __half22float2(h2[1]); acc[2] += w * f.x; acc[3] += w * f.y;
    f = __half22float2(h2[2]); acc[4] += w * f.x; acc[5] += w * f.y;
    f = __half22float2(h2[3]); acc[6] += w * f.x; acc[7] += w * f.y;
}

// ---- fp32 -> fp16 convert (8 elems/thread) --------------------------------

__global__ __launch_bounds__(THREADS) void f2h_kernel(
    const float* __restrict__ in, __half* __restrict__ out, int n8) {
    int i = blockIdx.x * THREADS + threadIdx.x;
    if (i < n8) {
        float4 a = ((const float4*)in)[i * 2];
        float4 b = ((const float4*)in)[i * 2 + 1];
        __half2 h[4] = {__floats2half2_rn(a.x, a.y), __floats2half2_rn(a.z, a.w),
                        __floats2half2_rn(b.x, b.y), __floats2half2_rn(b.z, b.w)};
        ((uint4*)out)[i] = *(uint4*)h;
    }
}

// ---- W[K][F] fp32 -> Wt[F][K] fp16 ----------------------------------------

__global__ __launch_bounds__(THREADS) void w2h_kernel(
    const float* __restrict__ W, __half* __restrict__ Wt, int K, int F) {
    int i = blockIdx.x * THREADS + threadIdx.x;
    if (i < K * F) {
        int k = i / F, f = i % F;
        Wt[f * K + k] = __float2half(W[i]);
    }
}

// ---- CSR build: bucketed counting sort, LDS-atomic only -------------------

__global__ __launch_bounds__(THREADS) void bucket_hist_kernel(
    const int* __restrict__ dst, int* __restrict__ bucketCnt, int E, int NBUCK) {
    __shared__ int lcnt[NBUCK_MAX];
    for (int i = threadIdx.x; i < NBUCK; i += THREADS) lcnt[i] = 0;
    __syncthreads();
    for (int e = blockIdx.x * THREADS + threadIdx.x; e < E; e += gridDim.x * THREADS)
        atomicAdd(&lcnt[dst[e] >> BSHIFT], 1);
    __syncthreads();
    for (int i = threadIdx.x; i < NBUCK; i += THREADS)
        if (lcnt[i]) atomicAdd(&bucketCnt[i], lcnt[i]);
}

__global__ __launch_bounds__(SCANT) void bucket_scan_kernel(
    const int* __restrict__ bucketCnt, int* __restrict__ bucketOff,
    int* __restrict__ bucketCur, int* __restrict__ rowptr, int NBUCK, int N) {
    __shared__ int s[SCANT];
    const int tid = threadIdx.x;
    int v = (tid < NBUCK) ? bucketCnt[tid] : 0;
    s[tid] = v;
    __syncthreads();
    for (int off = 1; off < SCANT; off <<= 1) {
        int t = 0;
        if (tid >= off) t = s[tid - off];
        __syncthreads();
        if (tid >= off) s[tid] += t;
        __syncthreads();
    }
    if (tid < NBUCK) {
        int ex = s[tid] - v;
        bucketOff[tid] = ex;
        bucketCur[tid] = ex;
    }
    if (tid == 0) {
        int total = s[SCANT - 1];
        bucketOff[NBUCK] = total;  // == E
        rowptr[N] = total;
    }
}

// packed edge record: (dst & (BNODES-1)) << 20 | src   (valid: N < 2^20)
__global__ __launch_bounds__(THREADS) void bucket_scatter_kernel(
    const int* __restrict__ src, const int* __restrict__ dst,
    int* __restrict__ bucketCur, int* __restrict__ ePack, int E, int NBUCK) {
    __shared__ int lcnt[NBUCK_MAX];
    __shared__ int lbase[NBUCK_MAX];
    for (int i = threadIdx.x; i < NBUCK; i += THREADS) lcnt[i] = 0;
    __syncthreads();
    const int base = blockIdx.x * CHUNK;
    int bk[EPT], rk[EPT], pk[EPT];
#pragma unroll
    for (int i = 0; i < EPT; ++i) {
        int e = base + i * THREADS + threadIdx.x;
        if (e < E) {
            int d = dst[e];
            pk[i] = ((d & (BNODES - 1)) << 20) | src[e];
            bk[i] = d >> BSHIFT;
            rk[i] = atomicAdd(&lcnt[bk[i]], 1);
        } else {
            bk[i] = -1;
        }
    }
    __syncthreads();
    for (int i = threadIdx.x; i < NBUCK; i += THREADS)
        if (lcnt[i]) lbase[i] = atomicAdd(&bucketCur[i], lcnt[i]);
    __syncthreads();
#pragma unroll
    for (int i = 0; i < EPT; ++i) {
        if (bk[i] >= 0) ePack[lbase[bk[i]] + rk[i]] = pk[i];
    }
}

// one block per bucket: LDS hist -> LDS scan -> rowptr/dinv/col
__global__ __launch_bounds__(THREADS) void build_kernel(
    const int* __restrict__ ePack, const int* __restrict__ bucketOff,
    int* __restrict__ rowptr, float* __restrict__ dinv,
    int* __restrict__ col, int N) {
    __shared__ int hist[BNODES];
    __shared__ int scn[BNODES];
    const int tid = threadIdx.x;
    const int b = blockIdx.x;
    const int off = bucketOff[b];
    const int end = bucketOff[b + 1];
    hist[tid] = 0;
    __syncthreads();
    for (int e = off + tid; e < end; e += THREADS)
        atomicAdd(&hist[((unsigned)ePack[e]) >> 20], 1);
    __syncthreads();
    int deg = hist[tid];
    scn[tid] = deg;
    __syncthreads();
    for (int o = 1; o < BNODES; o <<= 1) {
        int t = 0;
        if (tid >= o) t = scn[tid - o];
        __syncthreads();
        if (tid >= o) scn[tid] += t;
        __syncthreads();
    }
    int ex = off + scn[tid] - deg;
    const int node = (b << BSHIFT) + tid;
    if (node < N) {
        rowptr[node] = ex;
        dinv[node] = rsqrtf((float)deg + 1.0f);  // +1 self-loop
    }
    scn[tid] = ex;
    __syncthreads();
    for (int e = off + tid; e < end; e += THREADS) {
        int p = ePack[e];
        int pos = atomicAdd(&scn[((unsigned)p) >> 20], 1);
        col[pos] = p & 0xFFFFF;
    }
}

// ---- Aggregation F=64 (fp16 in): wave per row, 8 edges/iter ---------------

template <bool ACT, bool OUTH>
__global__ __launch_bounds__(THREADS) void agg64h_kernel(
    const __half* __restrict__ h, const int* __restrict__ rowptr,
    const int* __restrict__ col, const float* __restrict__ dinv,
    const float* __restrict__ bias, void* __restrict__ outv, int N) {
    const int lane = threadIdx.x & 63;
    const int r = blockIdx.x * 4 + (threadIdx.x >> 6);
    if (r >= N) return;
    const int oct = lane >> 3;
    const int sub = lane & 7;
    const uint4* __restrict__ h4 = (const uint4*)h;  // 8 uint4 per row
    const float dr = dinv[r];
    const int start = rowptr[r];
    const int end   = rowptr[r + 1];

    float acc[8] = {0.f, 0.f, 0.f, 0.f, 0.f, 0.f, 0.f, 0.f};
    if (oct == 0)
        acc8(acc, dr, h4[(size_t)r * 8 + sub]);

    for (int b = start; b < end; b += 64) {
        int m = end - b; if (m > 64) m = 64;
        int c = 0; float w = 0.0f;
        if (lane < m) { c = col[b + lane]; w = dinv[c]; }
#pragma unroll 2
        for (int j = 0; j < m; j += 8) {
            int   cj = __shfl(c, j + oct);
            float wj = __shfl(w, j + oct);
            acc8(acc, wj, h4[(size_t)cj * 8 + sub]);
        }
    }

#pragma unroll
    for (int off = 32; off >= 8; off >>= 1)
#pragma unroll
        for (int k = 0; k < 8; ++k)
            acc[k] += __shfl_xor(acc[k], off);

    if (oct == 0) {
        float res[8];
#pragma unroll
        for (int k = 0; k < 8; ++k) res[k] = acc[k] * dr;
        if constexpr (ACT) {
            const float* bp = bias + sub * 8;
#pragma unroll
            for (int k = 0; k < 8; ++k) res[k] = celu1(res[k] + bp[k]);
        }
        if constexpr (OUTH) {
            __half2 hp[4] = {__floats2half2_rn(res[0], res[1]), __floats2half2_rn(res[2], res[3]),
                             __floats2half2_rn(res[4], res[5]), __floats2half2_rn(res[6], res[7])};
            *(uint4*)((__half*)outv + (size_t)r * 64 + sub * 8) = *(uint4*)hp;
        } else {
            float4* o4 = (float4*)((float*)outv + (size_t)r * 64 + sub * 8);
            o4[0] = make_float4(res[0], res[1], res[2], res[3]);
            o4[1] = make_float4(res[4], res[5], res[6], res[7]);
        }
    }
}

// ---- Aggregation F=128 (fp16 in/out): wave per row, 4 edges/iter ----------

__global__ __launch_bounds__(THREADS) void agg128h_kernel(
    const __half* __restrict__ h, const int* __restrict__ rowptr,
    const int* __restrict__ col, const float* __restrict__ dinv,
    __half* __restrict__ out, int N) {
    const int lane = threadIdx.x & 63;
    const int r = blockIdx.x * 4 + (threadIdx.x >> 6);
    if (r >= N) return;
    const int quad = lane >> 4;
    const int sub  = lane & 15;
    const uint4* __restrict__ h4 = (const uint4*)h;  // 16 uint4 per row
    const float dr = dinv[r];
    const int start = rowptr[r];
    const int end   = rowptr[r + 1];

    float acc[8] = {0.f, 0.f, 0.f, 0.f, 0.f, 0.f, 0.f, 0.f};
    if (quad == 0)
        acc8(acc, dr, h4[(size_t)r * 16 + sub]);

    for (int b = start; b < end; b += 64) {
        int m = end - b; if (m > 64) m = 64;
        int c = 0; float w = 0.0f;
        if (lane < m) { c = col[b + lane]; w = dinv[c]; }
#pragma unroll 2
        for (int j = 0; j < m; j += 4) {
            int   cj = __shfl(c, j + quad);
            float wj = __shfl(w, j + quad);
            acc8(acc, wj, h4[(size_t)cj * 16 + sub]);
        }
    }

#pragma unroll
    for (int off = 32; off >= 16; off >>= 1)
#pragma unroll
        for (int k = 0; k < 8; ++k)
            acc[k] += __shfl_xor(acc[k], off);

    if (quad == 0) {
        __half2 hp[4] = {__floats2half2_rn(acc[0] * dr, acc[1] * dr),
                         __floats2half2_rn(acc[2] * dr, acc[3] * dr),
                         __floats2half2_rn(acc[4] * dr, acc[5] * dr),
                         __floats2half2_rn(acc[6] * dr, acc[7] * dr)};
        *(uint4*)(out + (size_t)r * 128 + sub * 8) = *(uint4*)hp;
    }
}

// ---- MFMA dense transform: out[N,F] = act(X[N,K] @ W[K,F] + b) ------------
// X fp16 row-major; Wt fp16 [F][K]. Wave: 16 rows x F cols, K-loop by 32.

template <int K, int F, bool ACT, bool HALF_OUT>
__global__ __launch_bounds__(THREADS) void mfma_gemm_kernel(
    const __half* __restrict__ X, const __half* __restrict__ Wt,
    const float* __restrict__ bias, void* __restrict__ outv, int N) {
    constexpr int KP = K + 8;  // padded LDS row stride (halves) — breaks bank conflict
    constexpr int NT = F / 16; // 16-col tiles
    __shared__ __half Ws[F * KP];

    const int tid = threadIdx.x;
    // stage Wt into LDS (16B chunks, rows padded)
    for (int i = tid; i < F * K / 8; i += THREADS) {
        int f = i / (K / 8), kg = i % (K / 8);
        *(uint4*)&Ws[f * KP + kg * 8] = ((const uint4*)Wt)[i];
    }
    __syncthreads();

    const int wave = tid >> 6, lane = tid & 63;
    const int q = lane >> 4, mn = lane & 15;
    const int row0w = blockIdx.x * 64 + wave * 16;
    int arow = row0w + mn;
    if (arow >= N) arow = N - 1;  // clamp loads; garbage rows masked on store

    floatx4 acc[NT];
#pragma unroll
    for (int t = 0; t < NT; ++t) acc[t] = {0.f, 0.f, 0.f, 0.f};

    const __half* xp = X + (size_t)arow * K + q * 8;
#pragma unroll
    for (int k0 = 0; k0 < K; k0 += 32) {
        half8 a = *(const half8*)(xp + k0);
#pragma unroll
        for (int t = 0; t < NT; ++t) {
            half8 b = *(const half8*)&Ws[(t * 16 + mn) * KP + k0 + q * 8];
            acc[t] = __builtin_amdgcn_mfma_f32_16x16x32_f16(a, b, acc[t], 0, 0, 0);
        }
    }

    // D: reg i <-> row = row0w + q*4 + i, col = t*16 + mn
    const int orow0 = row0w + q * 4;
#pragma unroll
    for (int t = 0; t < NT; ++t) {
        const int coln = t * 16 + mn;
        float bv = 0.f;
        if constexpr (ACT) bv = bias[coln];
#pragma unroll
        for (int i = 0; i < 4; ++i) {
            int r = orow0 + i;
            if (r < N) {
                float v = acc[t][i];
                if constexpr (ACT) v = celu1(v + bv);
                if constexpr (HALF_OUT)
                    ((__half*)outv)[(size_t)r * F + coln] = __float2half(v);
                else
                    ((float*)outv)[(size_t)r * F + coln] = v;
            }
        }
    }
}

// ---------------------------------------------------------------------------

extern "C" void kernel_launch(void* const* d_in, const int* in_sizes, int n_in,
                              void* d_out, int out_size, void* d_ws, size_t ws_size,
                              hipStream_t stream) {
    const float* x  = (const float*)d_in[0];
    const int*   ei = (const int*)d_in[1];
    const float* W1 = (const float*)d_in[2];
    const float* b1 = (const float*)d_in[3];
    const float* W2 = (const float*)d_in[4];
    const float* b2 = (const float*)d_in[5];
    const float* W3 = (const float*)d_in[6];
    const float* b3 = (const float*)d_in[7];
    float* out = (float*)d_out;

    const int N = in_sizes[0] / 64;   // 100000
    const int E = in_sizes[1] / 2;    // 1600000
    const int* src = ei;
    const int* dst = ei + E;
    const int NBUCK = (N + BNODES - 1) >> BSHIFT;  // 391

    char* p = (char*)d_ws;
    auto carve = [&](size_t bytes) {
        void* q = p;
        p += (bytes + 255) & ~(size_t)255;
        return q;
    };
    int*    rowptr    = (int*)carve((size_t)(N + 1) * sizeof(int));
    int*    col       = (int*)carve((size_t)E * sizeof(int));
    float*  dinv      = (float*)carve((size_t)N * sizeof(float));
    int*    bucketCnt = (int*)carve(NBUCK_MAX * sizeof(int));
    int*    bucketOff = (int*)carve((NBUCK_MAX + 1) * sizeof(int));
    int*    bucketCur = (int*)carve(NBUCK_MAX * sizeof(int));
    __half* xh        = (__half*)carve((size_t)N * 64 * sizeof(__half));
    __half* Wt1       = (__half*)carve(64 * 128 * sizeof(__half));
    __half* Wt2       = (__half*)carve(128 * 128 * sizeof(__half));
    __half* Wt3       = (__half*)carve(128 * 64 * sizeof(__half));
    __half* FA        = (__half*)carve((size_t)N * 128 * sizeof(__half));
    __half* FB        = (__half*)carve((size_t)N * 128 * sizeof(__half));
    int*    ePack     = (int*)FB;  // 6.4MB; consumed by build_kernel before gemm1 writes FB

    const int AB = (N + 3) / 4;
    const int GBM = (N + 63) / 64;
    const int SB = (E + CHUNK - 1) / CHUNK;
    const int FBk = (N * 8 + THREADS - 1) / THREADS;

    // --- CSR build + precision prep ---
    hipMemsetAsync(bucketCnt, 0, NBUCK_MAX * sizeof(int), stream);
    f2h_kernel<<<FBk, THREADS, 0, stream>>>(x, xh, N * 8);
    w2h_kernel<<<(64 * 128 + THREADS - 1) / THREADS, THREADS, 0, stream>>>(W1, Wt1, 64, 128);
    w2h_kernel<<<(128 * 128 + THREADS - 1) / THREADS, THREADS, 0, stream>>>(W2, Wt2, 128, 128);
    w2h_kernel<<<(128 * 64 + THREADS - 1) / THREADS, THREADS, 0, stream>>>(W3, Wt3, 128, 64);
    bucket_hist_kernel<<<256, THREADS, 0, stream>>>(dst, bucketCnt, E, NBUCK);
    bucket_scan_kernel<<<1, SCANT, 0, stream>>>(bucketCnt, bucketOff, bucketCur, rowptr, NBUCK, N);
    bucket_scatter_kernel<<<SB, THREADS, 0, stream>>>(src, dst, bucketCur, ePack, E, NBUCK);
    build_kernel<<<NBUCK, THREADS, 0, stream>>>(ePack, bucketOff, rowptr, dinv, col, N);

    // --- Layer 1: a1 = celu(Agg(x) @ W1 + b1) ---
    agg64h_kernel<false, true><<<AB, THREADS, 0, stream>>>(xh, rowptr, col, dinv, nullptr, FA, N);
    mfma_gemm_kernel<64, 128, true, true><<<GBM, THREADS, 0, stream>>>(FA, Wt1, b1, FB, N);

    // --- Layer 2: a2 = celu(Agg(a1) @ W2 + b2) ---
    agg128h_kernel<<<AB, THREADS, 0, stream>>>(FB, rowptr, col, dinv, FA, N);
    mfma_gemm_kernel<128, 128, true, true><<<GBM, THREADS, 0, stream>>>(FA, Wt2, b2, FB, N);

    // --- Layer 3: out = celu(Agg(a2 @ W3) + b3) ---
    mfma_gemm_kernel<128, 64, false, true><<<GBM, THREADS, 0, stream>>>(FB, Wt3, nullptr, FA, N);
    agg64h_kernel<true, false><<<AB, THREADS, 0, stream>>>(FA, rowptr, col, dinv, b3, out, N);
}

// Round 7
// 380.858 us; speedup vs baseline: 2.0542x; 1.0214x over previous
//
#include <hip/hip_runtime.h>
#include <hip/hip_fp16.h>
#include <math.h>

// ---------------------------------------------------------------------------
// 3-layer GCN. R2: bucketed CSR build. R3: fp16 gathers. R4: LDS-only CSR.
// R5: MFMA (16x16x32_f16) dense transforms, all inter-kernel buffers fp16.
// R6: algebraic pre-scaling — producers store g = dinv*h, so
//     Agg(r) = dinv[r] * (g[r] + sum_{s in N(r)} g[s]). The gather loop is a
//     pure unweighted fp16 row sum: no per-edge dinv gather, no shfl
//     broadcast (direct oct-uniform col loads), no per-edge multiply.
// ---------------------------------------------------------------------------

#define THREADS 256
#define SCANT 512
#define BSHIFT 8               // nodes per bucket = 256
#define BNODES (1 << BSHIFT)
#define NBUCK_MAX 512
#define EPT 16
#define CHUNK (THREADS * EPT)

typedef _Float16 half8 __attribute__((ext_vector_type(8)));
typedef float floatx4 __attribute__((ext_vector_type(4)));

__device__ __forceinline__ float celu1(float v) {
    return v > 0.0f ? v : expm1f(v);
}

__device__ __forceinline__ void add8(float* acc, uint4 u) {
    const __half2* h2 = (const __half2*)&u;
    float2 f;
    f = __half22float2(h2[0]); acc[0] += f.x; acc[1] += f.y;
    f = __half22float2(h2[1]); acc[2] += f.x; acc[3] += f.y;
    f = __half22float2(h2[2]); acc[4] += f.x; acc[5] += f.y;
    f = __half22float2(h2[3]); acc[6] += f.x; acc[7] += f.y;
}

// ---- x (fp32) -> g = dinv*x (fp16), 8 elems/thread ------------------------

__global__ __launch_bounds__(THREADS) void f2h_scale_kernel(
    const float* __restrict__ in, const float* __restrict__ dinv,
    __half* __restrict__ out, int n8) {
    int i = blockIdx.x * THREADS + threadIdx.x;
    if (i < n8) {
        float d = dinv[i >> 3];  // 8 elems/thread, 64 per row -> row = i/8
        float4 a = ((const float4*)in)[i * 2];
        float4 b = ((const float4*)in)[i * 2 + 1];
        __half2 h[4] = {__floats2half2_rn(a.x * d, a.y * d), __floats2half2_rn(a.z * d, a.w * d),
                        __floats2half2_rn(b.x * d, b.y * d), __floats2half2_rn(b.z * d, b.w * d)};
        ((uint4*)out)[i] = *(uint4*)h;
    }
}

// ---- W[K][F] fp32 -> Wt[F][K] fp16 ----------------------------------------

__global__ __launch_bounds__(THREADS) void w2h_kernel(
    const float* __restrict__ W, __half* __restrict__ Wt, int K, int F) {
    int i = blockIdx.x * THREADS + threadIdx.x;
    if (i < K * F) {
        int k = i / F, f = i % F;
        Wt[f * K + k] = __float2half(W[i]);
    }
}

// ---- CSR build: bucketed counting sort, LDS-atomic only -------------------

__global__ __launch_bounds__(THREADS) void bucket_hist_kernel(
    const int* __restrict__ dst, int* __restrict__ bucketCnt, int E, int NBUCK) {
    __shared__ int lcnt[NBUCK_MAX];
    for (int i = threadIdx.x; i < NBUCK; i += THREADS) lcnt[i] = 0;
    __syncthreads();
    for (int e = blockIdx.x * THREADS + threadIdx.x; e < E; e += gridDim.x * THREADS)
        atomicAdd(&lcnt[dst[e] >> BSHIFT], 1);
    __syncthreads();
    for (int i = threadIdx.x; i < NBUCK; i += THREADS)
        if (lcnt[i]) atomicAdd(&bucketCnt[i], lcnt[i]);
}

__global__ __launch_bounds__(SCANT) void bucket_scan_kernel(
    const int* __restrict__ bucketCnt, int* __restrict__ bucketOff,
    int* __restrict__ bucketCur, int* __restrict__ rowptr, int NBUCK, int N) {
    __shared__ int s[SCANT];
    const int tid = threadIdx.x;
    int v = (tid < NBUCK) ? bucketCnt[tid] : 0;
    s[tid] = v;
    __syncthreads();
    for (int off = 1; off < SCANT; off <<= 1) {
        int t = 0;
        if (tid >= off) t = s[tid - off];
        __syncthreads();
        if (tid >= off) s[tid] += t;
        __syncthreads();
    }
    if (tid < NBUCK) {
        int ex = s[tid] - v;
        bucketOff[tid] = ex;
        bucketCur[tid] = ex;
    }
    if (tid == 0) {
        int total = s[SCANT - 1];
        bucketOff[NBUCK] = total;  // == E
        rowptr[N] = total;
    }
}

// packed edge record: (dst & (BNODES-1)) << 20 | src   (valid: N < 2^20)
__global__ __launch_bounds__(THREADS) void bucket_scatter_kernel(
    const int* __restrict__ src, const int* __restrict__ dst,
    int* __restrict__ bucketCur, int* __restrict__ ePack, int E, int NBUCK) {
    __shared__ int lcnt[NBUCK_MAX];
    __shared__ int lbase[NBUCK_MAX];
    for (int i = threadIdx.x; i < NBUCK; i += THREADS) lcnt[i] = 0;
    __syncthreads();
    const int base = blockIdx.x * CHUNK;
    int bk[EPT], rk[EPT], pk[EPT];
#pragma unroll
    for (int i = 0; i < EPT; ++i) {
        int e = base + i * THREADS + threadIdx.x;
        if (e < E) {
            int d = dst[e];
            pk[i] = ((d & (BNODES - 1)) << 20) | src[e];
            bk[i] = d >> BSHIFT;
            rk[i] = atomicAdd(&lcnt[bk[i]], 1);
        } else {
            bk[i] = -1;
        }
    }
    __syncthreads();
    for (int i = threadIdx.x; i < NBUCK; i += THREADS)
        if (lcnt[i]) lbase[i] = atomicAdd(&bucketCur[i], lcnt[i]);
    __syncthreads();
#pragma unroll
    for (int i = 0; i < EPT; ++i) {
        if (bk[i] >= 0) ePack[lbase[bk[i]] + rk[i]] = pk[i];
    }
}

// one block per bucket: LDS hist -> LDS scan -> rowptr/dinv/col
__global__ __launch_bounds__(THREADS) void build_kernel(
    const int* __restrict__ ePack, const int* __restrict__ bucketOff,
    int* __restrict__ rowptr, float* __restrict__ dinv,
    int* __restrict__ col, int N) {
    __shared__ int hist[BNODES];
    __shared__ int scn[BNODES];
    const int tid = threadIdx.x;
    const int b = blockIdx.x;
    const int off = bucketOff[b];
    const int end = bucketOff[b + 1];
    hist[tid] = 0;
    __syncthreads();
    for (int e = off + tid; e < end; e += THREADS)
        atomicAdd(&hist[((unsigned)ePack[e]) >> 20], 1);
    __syncthreads();
    int deg = hist[tid];
    scn[tid] = deg;
    __syncthreads();
    for (int o = 1; o < BNODES; o <<= 1) {
        int t = 0;
        if (tid >= o) t = scn[tid - o];
        __syncthreads();
        if (tid >= o) scn[tid] += t;
        __syncthreads();
    }
    int ex = off + scn[tid] - deg;
    const int node = (b << BSHIFT) + tid;
    if (node < N) {
        rowptr[node] = ex;
        dinv[node] = rsqrtf((float)deg + 1.0f);  // +1 self-loop
    }
    scn[tid] = ex;
    __syncthreads();
    for (int e = off + tid; e < end; e += THREADS) {
        int p = ePack[e];
        int pos = atomicAdd(&scn[((unsigned)p) >> 20], 1);
        col[pos] = p & 0xFFFFF;
    }
}

// ---- Aggregation F=64 on pre-scaled g: wave/row, 8 edges in flight --------
// out(r) = dinv[r] * (g[r] + sum g[col]) [+bias, celu]. No weights, no shfl
// broadcast: each oct's 8 lanes load the oct-uniform col[e] directly.

template <bool ACT, bool OUTH>
__global__ __launch_bounds__(THREADS) void agg64g_kernel(
    const __half* __restrict__ g, const int* __restrict__ rowptr,
    const int* __restrict__ col, const float* __restrict__ dinv,
    const float* __restrict__ bias, void* __restrict__ outv, int N) {
    const int lane = threadIdx.x & 63;
    const int r = blockIdx.x * 4 + (threadIdx.x >> 6);
    if (r >= N) return;
    const int oct = lane >> 3;
    const int sub = lane & 7;
    const uint4* __restrict__ g4 = (const uint4*)g;  // 8 uint4 per row
    const int start = rowptr[r];
    const int end   = rowptr[r + 1];

    float acc[8] = {0.f, 0.f, 0.f, 0.f, 0.f, 0.f, 0.f, 0.f};
    if (oct == 0)  // self-loop: + g[r]
        add8(acc, g4[(size_t)r * 8 + sub]);

#pragma unroll 2
    for (int e = start + oct; e < end; e += 8) {
        int c = col[e];
        add8(acc, g4[(size_t)c * 8 + sub]);
    }

#pragma unroll
    for (int off = 32; off >= 8; off >>= 1)
#pragma unroll
        for (int k = 0; k < 8; ++k)
            acc[k] += __shfl_xor(acc[k], off);

    if (oct == 0) {
        const float dr = dinv[r];
        float res[8];
#pragma unroll
        for (int k = 0; k < 8; ++k) res[k] = acc[k] * dr;
        if constexpr (ACT) {
            const float* bp = bias + sub * 8;
#pragma unroll
            for (int k = 0; k < 8; ++k) res[k] = celu1(res[k] + bp[k]);
        }
        if constexpr (OUTH) {
            __half2 hp[4] = {__floats2half2_rn(res[0], res[1]), __floats2half2_rn(res[2], res[3]),
                             __floats2half2_rn(res[4], res[5]), __floats2half2_rn(res[6], res[7])};
            *(uint4*)((__half*)outv + (size_t)r * 64 + sub * 8) = *(uint4*)hp;
        } else {
            float4* o4 = (float4*)((float*)outv + (size_t)r * 64 + sub * 8);
            o4[0] = make_float4(res[0], res[1], res[2], res[3]);
            o4[1] = make_float4(res[4], res[5], res[6], res[7]);
        }
    }
}

// ---- Aggregation F=128 on pre-scaled g: wave/row, 4 edges in flight -------

__global__ __launch_bounds__(THREADS) void agg128g_kernel(
    const __half* __restrict__ g, const int* __restrict__ rowptr,
    const int* __restrict__ col, const float* __restrict__ dinv,
    __half* __restrict__ out, int N) {
    const int lane = threadIdx.x & 63;
    const int r = blockIdx.x * 4 + (threadIdx.x >> 6);
    if (r >= N) return;
    const int quad = lane >> 4;
    const int sub  = lane & 15;
    const uint4* __restrict__ g4 = (const uint4*)g;  // 16 uint4 per row
    const int start = rowptr[r];
    const int end   = rowptr[r + 1];

    float acc[8] = {0.f, 0.f, 0.f, 0.f, 0.f, 0.f, 0.f, 0.f};
    if (quad == 0)  // self-loop
        add8(acc, g4[(size_t)r * 16 + sub]);

#pragma unroll 2
    for (int e = start + quad; e < end; e += 4) {
        int c = col[e];
        add8(acc, g4[(size_t)c * 16 + sub]);
    }

#pragma unroll
    for (int off = 32; off >= 16; off >>= 1)
#pragma unroll
        for (int k = 0; k < 8; ++k)
            acc[k] += __shfl_xor(acc[k], off);

    if (quad == 0) {
        const float dr = dinv[r];
        __half2 hp[4] = {__floats2half2_rn(acc[0] * dr, acc[1] * dr),
                         __floats2half2_rn(acc[2] * dr, acc[3] * dr),
                         __floats2half2_rn(acc[4] * dr, acc[5] * dr),
                         __floats2half2_rn(acc[6] * dr, acc[7] * dr)};
        *(uint4*)(out + (size_t)r * 128 + sub * 8) = *(uint4*)hp;
    }
}

// ---- MFMA dense transform: out[N,F] = [dinv*] act(X @ W + b) --------------
// X fp16 row-major; Wt fp16 [F][K]. Wave: 16 rows x F cols, K-loop by 32.

template <int K, int F, bool ACT, bool SCALE>
__global__ __launch_bounds__(THREADS) void mfma_gemm_kernel(
    const __half* __restrict__ X, const __half* __restrict__ Wt,
    const float* __restrict__ bias, const float* __restrict__ dinv,
    __half* __restrict__ outh, int N) {
    constexpr int KP = K + 8;  // padded LDS row stride (halves)
    constexpr int NT = F / 16;
    __shared__ __half Ws[F * KP];

    const int tid = threadIdx.x;
    for (int i = tid; i < F * K / 8; i += THREADS) {
        int f = i / (K / 8), kg = i % (K / 8);
        *(uint4*)&Ws[f * KP + kg * 8] = ((const uint4*)Wt)[i];
    }
    __syncthreads();

    const int wave = tid >> 6, lane = tid & 63;
    const int q = lane >> 4, mn = lane & 15;
    const int row0w = blockIdx.x * 64 + wave * 16;
    int arow = row0w + mn;
    if (arow >= N) arow = N - 1;  // clamp loads; garbage rows masked on store

    floatx4 acc[NT];
#pragma unroll
    for (int t = 0; t < NT; ++t) acc[t] = {0.f, 0.f, 0.f, 0.f};

    const __half* xp = X + (size_t)arow * K + q * 8;
#pragma unroll
    for (int k0 = 0; k0 < K; k0 += 32) {
        half8 a = *(const half8*)(xp + k0);
#pragma unroll
        for (int t = 0; t < NT; ++t) {
            half8 b = *(const half8*)&Ws[(t * 16 + mn) * KP + k0 + q * 8];
            acc[t] = __builtin_amdgcn_mfma_f32_16x16x32_f16(a, b, acc[t], 0, 0, 0);
        }
    }

    // D: reg i <-> row = row0w + q*4 + i, col = t*16 + mn
    const int orow0 = row0w + q * 4;
    float dv[4] = {1.f, 1.f, 1.f, 1.f};
    if constexpr (SCALE) {
#pragma unroll
        for (int i = 0; i < 4; ++i) {
            int r = orow0 + i;
            if (r < N) dv[i] = dinv[r];
        }
    }
#pragma unroll
    for (int t = 0; t < NT; ++t) {
        const int coln = t * 16 + mn;
        float bv = 0.f;
        if constexpr (ACT) bv = bias[coln];
#pragma unroll
        for (int i = 0; i < 4; ++i) {
            int r = orow0 + i;
            if (r < N) {
                float v = acc[t][i];
                if constexpr (ACT) v = celu1(v + bv);
                if constexpr (SCALE) v *= dv[i];
                outh[(size_t)r * F + coln] = __float2half(v);
            }
        }
    }
}

// ---------------------------------------------------------------------------

extern "C" void kernel_launch(void* const* d_in, const int* in_sizes, int n_in,
                              void* d_out, int out_size, void* d_ws, size_t ws_size,
                              hipStream_t stream) {
    const float* x  = (const float*)d_in[0];
    const int*   ei = (const int*)d_in[1];
    const float* W1 = (const float*)d_in[2];
    const float* b1 = (const float*)d_in[3];
    const float* W2 = (const float*)d_in[4];
    const float* b2 = (const float*)d_in[5];
    const float* W3 = (const float*)d_in[6];
    const float* b3 = (const float*)d_in[7];
    float* out = (float*)d_out;

    const int N = in_sizes[0] / 64;   // 100000
    const int E = in_sizes[1] / 2;    // 1600000
    const int* src = ei;
    const int* dst = ei + E;
    const int NBUCK = (N + BNODES - 1) >> BSHIFT;  // 391

    char* p = (char*)d_ws;
    auto carve = [&](size_t bytes) {
        void* q = p;
        p += (bytes + 255) & ~(size_t)255;
        return q;
    };
    int*    rowptr    = (int*)carve((size_t)(N + 1) * sizeof(int));
    int*    col       = (int*)carve((size_t)E * sizeof(int));
    float*  dinv      = (float*)carve((size_t)N * sizeof(float));
    int*    bucketCnt = (int*)carve(NBUCK_MAX * sizeof(int));
    int*    bucketOff = (int*)carve((NBUCK_MAX + 1) * sizeof(int));
    int*    bucketCur = (int*)carve(NBUCK_MAX * sizeof(int));
    __half* xg        = (__half*)carve((size_t)N * 64 * sizeof(__half));
    __half* Wt1       = (__half*)carve(64 * 128 * sizeof(__half));
    __half* Wt2       = (__half*)carve(128 * 128 * sizeof(__half));
    __half* Wt3       = (__half*)carve(128 * 64 * sizeof(__half));
    __half* FA        = (__half*)carve((size_t)N * 128 * sizeof(__half));
    __half* FB        = (__half*)carve((size_t)N * 128 * sizeof(__half));
    int*    ePack     = (int*)FB;  // 6.4MB; consumed by build_kernel before gemm1 writes FB

    const int AB = (N + 3) / 4;
    const int GBM = (N + 63) / 64;
    const int SB = (E + CHUNK - 1) / CHUNK;
    const int FBk = (N * 8 + THREADS - 1) / THREADS;

    // --- CSR build, then precision prep (f2h needs dinv) ---
    hipMemsetAsync(bucketCnt, 0, NBUCK_MAX * sizeof(int), stream);
    bucket_hist_kernel<<<256, THREADS, 0, stream>>>(dst, bucketCnt, E, NBUCK);
    bucket_scan_kernel<<<1, SCANT, 0, stream>>>(bucketCnt, bucketOff, bucketCur, rowptr, NBUCK, N);
    bucket_scatter_kernel<<<SB, THREADS, 0, stream>>>(src, dst, bucketCur, ePack, E, NBUCK);
    build_kernel<<<NBUCK, THREADS, 0, stream>>>(ePack, bucketOff, rowptr, dinv, col, N);
    f2h_scale_kernel<<<FBk, THREADS, 0, stream>>>(x, dinv, xg, N * 8);
    w2h_kernel<<<(64 * 128 + THREADS - 1) / THREADS, THREADS, 0, stream>>>(W1, Wt1, 64, 128);
    w2h_kernel<<<(128 * 128 + THREADS - 1) / THREADS, THREADS, 0, stream>>>(W2, Wt2, 128, 128);
    w2h_kernel<<<(128 * 64 + THREADS - 1) / THREADS, THREADS, 0, stream>>>(W3, Wt3, 128, 64);

    // --- Layer 1: s1 = Agg(x);  g1 = dinv*celu(s1@W1+b1)  (pre-scaled) ---
    agg64g_kernel<false, true><<<AB, THREADS, 0, stream>>>(xg, rowptr, col, dinv, nullptr, FA, N);
    mfma_gemm_kernel<64, 128, true, true><<<GBM, THREADS, 0, stream>>>(FA, Wt1, b1, dinv, FB, N);

    // --- Layer 2: s2 = Agg(a1);  a2 = celu(s2@W2+b2)  (NOT pre-scaled) ---
    agg128g_kernel<<<AB, THREADS, 0, stream>>>(FB, rowptr, col, dinv, FA, N);
    mfma_gemm_kernel<128, 128, true, false><<<GBM, THREADS, 0, stream>>>(FA, Wt2, b2, dinv, FB, N);

    // --- Layer 3: g3 = dinv*(a2@W3); out = celu(dinv*(g3[r]+sum g3)+b3) ---
    mfma_gemm_kernel<128, 64, false, true><<<GBM, THREADS, 0, stream>>>(FB, Wt3, nullptr, dinv, FA, N);
    agg64g_kernel<true, false><<<AB, THREADS, 0, stream>>>(FA, rowptr, col, dinv, b3, out, N);
}

// Round 8
// 342.799 us; speedup vs baseline: 2.2823x; 1.1110x over previous
//
#include <hip/hip_runtime.h>
#include <hip/hip_fp16.h>
#include <math.h>

// ---------------------------------------------------------------------------
// 3-layer GCN. R2: bucketed CSR build. R3: fp16 gathers. R4: LDS-only CSR.
// R5: MFMA dense transforms, fp16 inter-kernel buffers. R6: pre-scaled g.
// R7: oct-per-row aggregation — 8 lanes own a whole F=64 row (16 lanes for
//     F=128). No cross-lane reduction butterfly (was ~80 inst/row vs ~2
//     useful gather iters at mean degree 16). Divergent per-group edge loop,
//     unrolled x2 for memory-level parallelism.
// ---------------------------------------------------------------------------

#define THREADS 256
#define SCANT 512
#define BSHIFT 8               // nodes per bucket = 256
#define BNODES (1 << BSHIFT)
#define NBUCK_MAX 512
#define EPT 16
#define CHUNK (THREADS * EPT)

typedef _Float16 half8 __attribute__((ext_vector_type(8)));
typedef float floatx4 __attribute__((ext_vector_type(4)));

__device__ __forceinline__ float celu1(float v) {
    return v > 0.0f ? v : expm1f(v);
}

__device__ __forceinline__ void add8(float* acc, uint4 u) {
    const __half2* h2 = (const __half2*)&u;
    float2 f;
    f = __half22float2(h2[0]); acc[0] += f.x; acc[1] += f.y;
    f = __half22float2(h2[1]); acc[2] += f.x; acc[3] += f.y;
    f = __half22float2(h2[2]); acc[4] += f.x; acc[5] += f.y;
    f = __half22float2(h2[3]); acc[6] += f.x; acc[7] += f.y;
}

// ---- x (fp32) -> g = dinv*x (fp16), 8 elems/thread ------------------------

__global__ __launch_bounds__(THREADS) void f2h_scale_kernel(
    const float* __restrict__ in, const float* __restrict__ dinv,
    __half* __restrict__ out, int n8) {
    int i = blockIdx.x * THREADS + threadIdx.x;
    if (i < n8) {
        float d = dinv[i >> 3];  // 8 elems/thread, 64 per row -> row = i/8
        float4 a = ((const float4*)in)[i * 2];
        float4 b = ((const float4*)in)[i * 2 + 1];
        __half2 h[4] = {__floats2half2_rn(a.x * d, a.y * d), __floats2half2_rn(a.z * d, a.w * d),
                        __floats2half2_rn(b.x * d, b.y * d), __floats2half2_rn(b.z * d, b.w * d)};
        ((uint4*)out)[i] = *(uint4*)h;
    }
}

// ---- W[K][F] fp32 -> Wt[F][K] fp16 ----------------------------------------

__global__ __launch_bounds__(THREADS) void w2h_kernel(
    const float* __restrict__ W, __half* __restrict__ Wt, int K, int F) {
    int i = blockIdx.x * THREADS + threadIdx.x;
    if (i < K * F) {
        int k = i / F, f = i % F;
        Wt[f * K + k] = __float2half(W[i]);
    }
}

// ---- CSR build: bucketed counting sort, LDS-atomic only -------------------

__global__ __launch_bounds__(THREADS) void bucket_hist_kernel(
    const int* __restrict__ dst, int* __restrict__ bucketCnt, int E, int NBUCK) {
    __shared__ int lcnt[NBUCK_MAX];
    for (int i = threadIdx.x; i < NBUCK; i += THREADS) lcnt[i] = 0;
    __syncthreads();
    for (int e = blockIdx.x * THREADS + threadIdx.x; e < E; e += gridDim.x * THREADS)
        atomicAdd(&lcnt[dst[e] >> BSHIFT], 1);
    __syncthreads();
    for (int i = threadIdx.x; i < NBUCK; i += THREADS)
        if (lcnt[i]) atomicAdd(&bucketCnt[i], lcnt[i]);
}

__global__ __launch_bounds__(SCANT) void bucket_scan_kernel(
    const int* __restrict__ bucketCnt, int* __restrict__ bucketOff,
    int* __restrict__ bucketCur, int* __restrict__ rowptr, int NBUCK, int N) {
    __shared__ int s[SCANT];
    const int tid = threadIdx.x;
    int v = (tid < NBUCK) ? bucketCnt[tid] : 0;
    s[tid] = v;
    __syncthreads();
    for (int off = 1; off < SCANT; off <<= 1) {
        int t = 0;
        if (tid >= off) t = s[tid - off];
        __syncthreads();
        if (tid >= off) s[tid] += t;
        __syncthreads();
    }
    if (tid < NBUCK) {
        int ex = s[tid] - v;
        bucketOff[tid] = ex;
        bucketCur[tid] = ex;
    }
    if (tid == 0) {
        int total = s[SCANT - 1];
        bucketOff[NBUCK] = total;  // == E
        rowptr[N] = total;
    }
}

// packed edge record: (dst & (BNODES-1)) << 20 | src   (valid: N < 2^20)
__global__ __launch_bounds__(THREADS) void bucket_scatter_kernel(
    const int* __restrict__ src, const int* __restrict__ dst,
    int* __restrict__ bucketCur, int* __restrict__ ePack, int E, int NBUCK) {
    __shared__ int lcnt[NBUCK_MAX];
    __shared__ int lbase[NBUCK_MAX];
    for (int i = threadIdx.x; i < NBUCK; i += THREADS) lcnt[i] = 0;
    __syncthreads();
    const int base = blockIdx.x * CHUNK;
    int bk[EPT], rk[EPT], pk[EPT];
#pragma unroll
    for (int i = 0; i < EPT; ++i) {
        int e = base + i * THREADS + threadIdx.x;
        if (e < E) {
            int d = dst[e];
            pk[i] = ((d & (BNODES - 1)) << 20) | src[e];
            bk[i] = d >> BSHIFT;
            rk[i] = atomicAdd(&lcnt[bk[i]], 1);
        } else {
            bk[i] = -1;
        }
    }
    __syncthreads();
    for (int i = threadIdx.x; i < NBUCK; i += THREADS)
        if (lcnt[i]) lbase[i] = atomicAdd(&bucketCur[i], lcnt[i]);
    __syncthreads();
#pragma unroll
    for (int i = 0; i < EPT; ++i) {
        if (bk[i] >= 0) ePack[lbase[bk[i]] + rk[i]] = pk[i];
    }
}

// one block per bucket: LDS hist -> LDS scan -> rowptr/dinv/col
__global__ __launch_bounds__(THREADS) void build_kernel(
    const int* __restrict__ ePack, const int* __restrict__ bucketOff,
    int* __restrict__ rowptr, float* __restrict__ dinv,
    int* __restrict__ col, int N) {
    __shared__ int hist[BNODES];
    __shared__ int scn[BNODES];
    const int tid = threadIdx.x;
    const int b = blockIdx.x;
    const int off = bucketOff[b];
    const int end = bucketOff[b + 1];
    hist[tid] = 0;
    __syncthreads();
    for (int e = off + tid; e < end; e += THREADS)
        atomicAdd(&hist[((unsigned)ePack[e]) >> 20], 1);
    __syncthreads();
    int deg = hist[tid];
    scn[tid] = deg;
    __syncthreads();
    for (int o = 1; o < BNODES; o <<= 1) {
        int t = 0;
        if (tid >= o) t = scn[tid - o];
        __syncthreads();
        if (tid >= o) scn[tid] += t;
        __syncthreads();
    }
    int ex = off + scn[tid] - deg;
    const int node = (b << BSHIFT) + tid;
    if (node < N) {
        rowptr[node] = ex;
        dinv[node] = rsqrtf((float)deg + 1.0f);  // +1 self-loop
    }
    scn[tid] = ex;
    __syncthreads();
    for (int e = off + tid; e < end; e += THREADS) {
        int p = ePack[e];
        int pos = atomicAdd(&scn[((unsigned)p) >> 20], 1);
        col[pos] = p & 0xFFFFF;
    }
}

// ---- Aggregation F=64: one oct (8 lanes) per row --------------------------
// out(r) = dinv[r]*(g[r] + sum g[col]). 32 rows/block. No cross-lane reduce.

template <bool ACT, bool OUTH>
__global__ __launch_bounds__(THREADS) void agg64g_kernel(
    const __half* __restrict__ g, const int* __restrict__ rowptr,
    const int* __restrict__ col, const float* __restrict__ dinv,
    const float* __restrict__ bias, void* __restrict__ outv, int N) {
    const int tid = threadIdx.x;
    const int lane = tid & 63, wave = tid >> 6;
    const int oct = lane >> 3, sub = lane & 7;
    const int r = blockIdx.x * 32 + wave * 8 + oct;
    const uint4* __restrict__ g4 = (const uint4*)g;  // 8 uint4 per row
    const bool valid = (r < N);
    int start = 0, end = 0;
    if (valid) { start = rowptr[r]; end = rowptr[r + 1]; }

    float acc[8] = {0.f, 0.f, 0.f, 0.f, 0.f, 0.f, 0.f, 0.f};
    if (valid) add8(acc, g4[(size_t)r * 8 + sub]);  // self-loop

    int e = start;
    for (; e + 2 <= end; e += 2) {
        int c0 = col[e], c1 = col[e + 1];
        uint4 u0 = g4[(size_t)c0 * 8 + sub];
        uint4 u1 = g4[(size_t)c1 * 8 + sub];
        add8(acc, u0);
        add8(acc, u1);
    }
    if (e < end) add8(acc, g4[(size_t)col[e] * 8 + sub]);

    if (valid) {
        const float dr = dinv[r];
        float res[8];
#pragma unroll
        for (int k = 0; k < 8; ++k) res[k] = acc[k] * dr;
        if constexpr (ACT) {
            const float* bp = bias + sub * 8;
#pragma unroll
            for (int k = 0; k < 8; ++k) res[k] = celu1(res[k] + bp[k]);
        }
        if constexpr (OUTH) {
            __half2 hp[4] = {__floats2half2_rn(res[0], res[1]), __floats2half2_rn(res[2], res[3]),
                             __floats2half2_rn(res[4], res[5]), __floats2half2_rn(res[6], res[7])};
            *(uint4*)((__half*)outv + (size_t)r * 64 + sub * 8) = *(uint4*)hp;
        } else {
            float4* o4 = (float4*)((float*)outv + (size_t)r * 64 + sub * 8);
            o4[0] = make_float4(res[0], res[1], res[2], res[3]);
            o4[1] = make_float4(res[4], res[5], res[6], res[7]);
        }
    }
}

// ---- Aggregation F=128: one 16-lane group per row -------------------------

__global__ __launch_bounds__(THREADS) void agg128g_kernel(
    const __half* __restrict__ g, const int* __restrict__ rowptr,
    const int* __restrict__ col, const float* __restrict__ dinv,
    __half* __restrict__ out, int N) {
    const int tid = threadIdx.x;
    const int lane = tid & 63, wave = tid >> 6;
    const int grp = lane >> 4, sub = lane & 15;
    const int r = blockIdx.x * 16 + wave * 4 + grp;
    const uint4* __restrict__ g4 = (const uint4*)g;  // 16 uint4 per row
    const bool valid = (r < N);
    int start = 0, end = 0;
    if (valid) { start = rowptr[r]; end = rowptr[r + 1]; }

    float acc[8] = {0.f, 0.f, 0.f, 0.f, 0.f, 0.f, 0.f, 0.f};
    if (valid) add8(acc, g4[(size_t)r * 16 + sub]);  // self-loop

    int e = start;
    for (; e + 2 <= end; e += 2) {
        int c0 = col[e], c1 = col[e + 1];
        uint4 u0 = g4[(size_t)c0 * 16 + sub];
        uint4 u1 = g4[(size_t)c1 * 16 + sub];
        add8(acc, u0);
        add8(acc, u1);
    }
    if (e < end) add8(acc, g4[(size_t)col[e] * 16 + sub]);

    if (valid) {
        const float dr = dinv[r];
        __half2 hp[4] = {__floats2half2_rn(acc[0] * dr, acc[1] * dr),
                         __floats2half2_rn(acc[2] * dr, acc[3] * dr),
                         __floats2half2_rn(acc[4] * dr, acc[5] * dr),
                         __floats2half2_rn(acc[6] * dr, acc[7] * dr)};
        *(uint4*)(out + (size_t)r * 128 + sub * 8) = *(uint4*)hp;
    }
}

// ---- MFMA dense transform: out[N,F] = [dinv*] act(X @ W + b) --------------

template <int K, int F, bool ACT, bool SCALE>
__global__ __launch_bounds__(THREADS) void mfma_gemm_kernel(
    const __half* __restrict__ X, const __half* __restrict__ Wt,
    const float* __restrict__ bias, const float* __restrict__ dinv,
    __half* __restrict__ outh, int N) {
    constexpr int KP = K + 8;  // padded LDS row stride (halves)
    constexpr int NT = F / 16;
    __shared__ __half Ws[F * KP];

    const int tid = threadIdx.x;
    for (int i = tid; i < F * K / 8; i += THREADS) {
        int f = i / (K / 8), kg = i % (K / 8);
        *(uint4*)&Ws[f * KP + kg * 8] = ((const uint4*)Wt)[i];
    }
    __syncthreads();

    const int wave = tid >> 6, lane = tid & 63;
    const int q = lane >> 4, mn = lane & 15;
    const int row0w = blockIdx.x * 64 + wave * 16;
    int arow = row0w + mn;
    if (arow >= N) arow = N - 1;  // clamp loads; garbage rows masked on store

    floatx4 acc[NT];
#pragma unroll
    for (int t = 0; t < NT; ++t) acc[t] = {0.f, 0.f, 0.f, 0.f};

    const __half* xp = X + (size_t)arow * K + q * 8;
#pragma unroll
    for (int k0 = 0; k0 < K; k0 += 32) {
        half8 a = *(const half8*)(xp + k0);
#pragma unroll
        for (int t = 0; t < NT; ++t) {
            half8 b = *(const half8*)&Ws[(t * 16 + mn) * KP + k0 + q * 8];
            acc[t] = __builtin_amdgcn_mfma_f32_16x16x32_f16(a, b, acc[t], 0, 0, 0);
        }
    }

    // D: reg i <-> row = row0w + q*4 + i, col = t*16 + mn
    const int orow0 = row0w + q * 4;
    float dv[4] = {1.f, 1.f, 1.f, 1.f};
    if constexpr (SCALE) {
#pragma unroll
        for (int i = 0; i < 4; ++i) {
            int r = orow0 + i;
            if (r < N) dv[i] = dinv[r];
        }
    }
#pragma unroll
    for (int t = 0; t < NT; ++t) {
        const int coln = t * 16 + mn;
        float bv = 0.f;
        if constexpr (ACT) bv = bias[coln];
#pragma unroll
        for (int i = 0; i < 4; ++i) {
            int r = orow0 + i;
            if (r < N) {
                float v = acc[t][i];
                if constexpr (ACT) v = celu1(v + bv);
                if constexpr (SCALE) v *= dv[i];
                outh[(size_t)r * F + coln] = __float2half(v);
            }
        }
    }
}

// ---------------------------------------------------------------------------

extern "C" void kernel_launch(void* const* d_in, const int* in_sizes, int n_in,
                              void* d_out, int out_size, void* d_ws, size_t ws_size,
                              hipStream_t stream) {
    const float* x  = (const float*)d_in[0];
    const int*   ei = (const int*)d_in[1];
    const float* W1 = (const float*)d_in[2];
    const float* b1 = (const float*)d_in[3];
    const float* W2 = (const float*)d_in[4];
    const float* b2 = (const float*)d_in[5];
    const float* W3 = (const float*)d_in[6];
    const float* b3 = (const float*)d_in[7];
    float* out = (float*)d_out;

    const int N = in_sizes[0] / 64;   // 100000
    const int E = in_sizes[1] / 2;    // 1600000
    const int* src = ei;
    const int* dst = ei + E;
    const int NBUCK = (N + BNODES - 1) >> BSHIFT;  // 391

    char* p = (char*)d_ws;
    auto carve = [&](size_t bytes) {
        void* q = p;
        p += (bytes + 255) & ~(size_t)255;
        return q;
    };
    int*    rowptr    = (int*)carve((size_t)(N + 1) * sizeof(int));
    int*    col       = (int*)carve((size_t)E * sizeof(int));
    float*  dinv      = (float*)carve((size_t)N * sizeof(float));
    int*    bucketCnt = (int*)carve(NBUCK_MAX * sizeof(int));
    int*    bucketOff = (int*)carve((NBUCK_MAX + 1) * sizeof(int));
    int*    bucketCur = (int*)carve(NBUCK_MAX * sizeof(int));
    __half* xg        = (__half*)carve((size_t)N * 64 * sizeof(__half));
    __half* Wt1       = (__half*)carve(64 * 128 * sizeof(__half));
    __half* Wt2       = (__half*)carve(128 * 128 * sizeof(__half));
    __half* Wt3       = (__half*)carve(128 * 64 * sizeof(__half));
    __half* FA        = (__half*)carve((size_t)N * 128 * sizeof(__half));
    __half* FB        = (__half*)carve((size_t)N * 128 * sizeof(__half));
    int*    ePack     = (int*)FB;  // 6.4MB; consumed by build_kernel before gemm1 writes FB

    const int AB64  = (N + 31) / 32;
    const int AB128 = (N + 15) / 16;
    const int GBM = (N + 63) / 64;
    const int SB = (E + CHUNK - 1) / CHUNK;
    const int FBk = (N * 8 + THREADS - 1) / THREADS;

    // --- CSR build, then precision prep (f2h needs dinv) ---
    hipMemsetAsync(bucketCnt, 0, NBUCK_MAX * sizeof(int), stream);
    bucket_hist_kernel<<<256, THREADS, 0, stream>>>(dst, bucketCnt, E, NBUCK);
    bucket_scan_kernel<<<1, SCANT, 0, stream>>>(bucketCnt, bucketOff, bucketCur, rowptr, NBUCK, N);
    bucket_scatter_kernel<<<SB, THREADS, 0, stream>>>(src, dst, bucketCur, ePack, E, NBUCK);
    build_kernel<<<NBUCK, THREADS, 0, stream>>>(ePack, bucketOff, rowptr, dinv, col, N);
    f2h_scale_kernel<<<FBk, THREADS, 0, stream>>>(x, dinv, xg, N * 8);
    w2h_kernel<<<(64 * 128 + THREADS - 1) / THREADS, THREADS, 0, stream>>>(W1, Wt1, 64, 128);
    w2h_kernel<<<(128 * 128 + THREADS - 1) / THREADS, THREADS, 0, stream>>>(W2, Wt2, 128, 128);
    w2h_kernel<<<(128 * 64 + THREADS - 1) / THREADS, THREADS, 0, stream>>>(W3, Wt3, 128, 64);

    // --- Layer 1: s1 = Agg(x);  g1 = dinv*celu(s1@W1+b1)  (pre-scaled) ---
    agg64g_kernel<false, true><<<AB64, THREADS, 0, stream>>>(xg, rowptr, col, dinv, nullptr, FA, N);
    mfma_gemm_kernel<64, 128, true, true><<<GBM, THREADS, 0, stream>>>(FA, Wt1, b1, dinv, FB, N);

    // --- Layer 2: s2 = Agg(g1);  a2 = celu(s2@W2+b2)  (NOT pre-scaled) ---
    agg128g_kernel<<<AB128, THREADS, 0, stream>>>(FB, rowptr, col, dinv, FA, N);
    mfma_gemm_kernel<128, 128, true, false><<<GBM, THREADS, 0, stream>>>(FA, Wt2, b2, dinv, FB, N);

    // --- Layer 3: g3 = dinv*(a2@W3); out = celu(dinv*(g3[r]+sum g3)+b3) ---
    mfma_gemm_kernel<128, 64, false, true><<<GBM, THREADS, 0, stream>>>(FB, Wt3, nullptr, dinv, FA, N);
    agg64g_kernel<true, false><<<AB64, THREADS, 0, stream>>>(FA, rowptr, col, dinv, b3, out, N);
}

// Round 9
// 327.514 us; speedup vs baseline: 2.3888x; 1.0467x over previous
//
#include <hip/hip_runtime.h>
#include <hip/hip_fp16.h>
#include <math.h>

// ---------------------------------------------------------------------------
// 3-layer GCN. R2: bucketed CSR build. R3: fp16 gathers. R4: LDS-only CSR.
// R5: MFMA dense transforms, fp16 buffers. R6: pre-scaled g (no per-edge
// weights). R7: oct/16-lane-group per row (no reduction butterfly).
// R8: unroll-4 gather loop (4 outstanding col+row loads per group), fused
//     prep kernel (f2h+3xw2h), int4 bucket_hist reads.
// ---------------------------------------------------------------------------

#define THREADS 256
#define SCANT 512
#define BSHIFT 8               // nodes per bucket = 256
#define BNODES (1 << BSHIFT)
#define NBUCK_MAX 512
#define EPT 16
#define CHUNK (THREADS * EPT)

typedef _Float16 half8 __attribute__((ext_vector_type(8)));
typedef float floatx4 __attribute__((ext_vector_type(4)));

__device__ __forceinline__ float celu1(float v) {
    return v > 0.0f ? v : expm1f(v);
}

__device__ __forceinline__ void add8(float* acc, uint4 u) {
    const __half2* h2 = (const __half2*)&u;
    float2 f;
    f = __half22float2(h2[0]); acc[0] += f.x; acc[1] += f.y;
    f = __half22float2(h2[1]); acc[2] += f.x; acc[3] += f.y;
    f = __half22float2(h2[2]); acc[4] += f.x; acc[5] += f.y;
    f = __half22float2(h2[3]); acc[6] += f.x; acc[7] += f.y;
}

// ---- fused prep: xg = dinv*x (fp16) ; Wt = W^T (fp16) ---------------------

__global__ __launch_bounds__(THREADS) void prep_kernel(
    const float* __restrict__ x, const float* __restrict__ dinv,
    __half* __restrict__ xg,
    const float* __restrict__ W1, __half* __restrict__ Wt1,
    const float* __restrict__ W2, __half* __restrict__ Wt2,
    const float* __restrict__ W3, __half* __restrict__ Wt3, int n8) {
    const int nf2h = (n8 + THREADS - 1) / THREADS;  // blocks for f2h part
    int b = blockIdx.x;
    if (b < nf2h) {
        int i = b * THREADS + threadIdx.x;
        if (i < n8) {
            float d = dinv[i >> 3];
            float4 a = ((const float4*)x)[i * 2];
            float4 c = ((const float4*)x)[i * 2 + 1];
            __half2 h[4] = {__floats2half2_rn(a.x * d, a.y * d), __floats2half2_rn(a.z * d, a.w * d),
                            __floats2half2_rn(c.x * d, c.y * d), __floats2half2_rn(c.z * d, c.w * d)};
            ((uint4*)xg)[i] = *(uint4*)h;
        }
        return;
    }
    b -= nf2h;
    // w2h: W1 8192 elems (32 blocks), W2 16384 (64), W3 8192 (32)
    const float* W; __half* Wt; int K, F;
    if (b < 32)      { W = W1; Wt = Wt1; K = 64;  F = 128; }
    else if (b < 96) { W = W2; Wt = Wt2; K = 128; F = 128; b -= 32; }
    else             { W = W3; Wt = Wt3; K = 128; F = 64;  b -= 96; }
    int i = b * THREADS + threadIdx.x;
    if (i < K * F) {
        int k = i / F, f = i % F;
        Wt[f * K + k] = __float2half(W[i]);
    }
}

// ---- CSR build: bucketed counting sort, LDS-atomic only -------------------

__global__ __launch_bounds__(THREADS) void bucket_hist_kernel(
    const int* __restrict__ dst, int* __restrict__ bucketCnt, int E, int NBUCK) {
    __shared__ int lcnt[NBUCK_MAX];
    for (int i = threadIdx.x; i < NBUCK; i += THREADS) lcnt[i] = 0;
    __syncthreads();
    const int E4 = E >> 2;
    for (int e4 = blockIdx.x * THREADS + threadIdx.x; e4 < E4; e4 += gridDim.x * THREADS) {
        int4 d = ((const int4*)dst)[e4];
        atomicAdd(&lcnt[d.x >> BSHIFT], 1);
        atomicAdd(&lcnt[d.y >> BSHIFT], 1);
        atomicAdd(&lcnt[d.z >> BSHIFT], 1);
        atomicAdd(&lcnt[d.w >> BSHIFT], 1);
    }
    // tail
    if (blockIdx.x == 0) {
        for (int e = (E4 << 2) + threadIdx.x; e < E; e += THREADS)
            atomicAdd(&lcnt[dst[e] >> BSHIFT], 1);
    }
    __syncthreads();
    for (int i = threadIdx.x; i < NBUCK; i += THREADS)
        if (lcnt[i]) atomicAdd(&bucketCnt[i], lcnt[i]);
}

__global__ __launch_bounds__(SCANT) void bucket_scan_kernel(
    const int* __restrict__ bucketCnt, int* __restrict__ bucketOff,
    int* __restrict__ bucketCur, int* __restrict__ rowptr, int NBUCK, int N) {
    __shared__ int s[SCANT];
    const int tid = threadIdx.x;
    int v = (tid < NBUCK) ? bucketCnt[tid] : 0;
    s[tid] = v;
    __syncthreads();
    for (int off = 1; off < SCANT; off <<= 1) {
        int t = 0;
        if (tid >= off) t = s[tid - off];
        __syncthreads();
        if (tid >= off) s[tid] += t;
        __syncthreads();
    }
    if (tid < NBUCK) {
        int ex = s[tid] - v;
        bucketOff[tid] = ex;
        bucketCur[tid] = ex;
    }
    if (tid == 0) {
        int total = s[SCANT - 1];
        bucketOff[NBUCK] = total;  // == E
        rowptr[N] = total;
    }
}

// packed edge record: (dst & (BNODES-1)) << 20 | src   (valid: N < 2^20)
__global__ __launch_bounds__(THREADS) void bucket_scatter_kernel(
    const int* __restrict__ src, const int* __restrict__ dst,
    int* __restrict__ bucketCur, int* __restrict__ ePack, int E, int NBUCK) {
    __shared__ int lcnt[NBUCK_MAX];
    __shared__ int lbase[NBUCK_MAX];
    for (int i = threadIdx.x; i < NBUCK; i += THREADS) lcnt[i] = 0;
    __syncthreads();
    const int base = blockIdx.x * CHUNK;
    int bk[EPT], rk[EPT], pk[EPT];
#pragma unroll
    for (int i = 0; i < EPT; ++i) {
        int e = base + i * THREADS + threadIdx.x;
        if (e < E) {
            int d = dst[e];
            pk[i] = ((d & (BNODES - 1)) << 20) | src[e];
            bk[i] = d >> BSHIFT;
            rk[i] = atomicAdd(&lcnt[bk[i]], 1);
        } else {
            bk[i] = -1;
        }
    }
    __syncthreads();
    for (int i = threadIdx.x; i < NBUCK; i += THREADS)
        if (lcnt[i]) lbase[i] = atomicAdd(&bucketCur[i], lcnt[i]);
    __syncthreads();
#pragma unroll
    for (int i = 0; i < EPT; ++i) {
        if (bk[i] >= 0) ePack[lbase[bk[i]] + rk[i]] = pk[i];
    }
}

// one block per bucket: LDS hist -> LDS scan -> rowptr/dinv/col
__global__ __launch_bounds__(THREADS) void build_kernel(
    const int* __restrict__ ePack, const int* __restrict__ bucketOff,
    int* __restrict__ rowptr, float* __restrict__ dinv,
    int* __restrict__ col, int N) {
    __shared__ int hist[BNODES];
    __shared__ int scn[BNODES];
    const int tid = threadIdx.x;
    const int b = blockIdx.x;
    const int off = bucketOff[b];
    const int end = bucketOff[b + 1];
    hist[tid] = 0;
    __syncthreads();
    for (int e = off + tid; e < end; e += THREADS)
        atomicAdd(&hist[((unsigned)ePack[e]) >> 20], 1);
    __syncthreads();
    int deg = hist[tid];
    scn[tid] = deg;
    __syncthreads();
    for (int o = 1; o < BNODES; o <<= 1) {
        int t = 0;
        if (tid >= o) t = scn[tid - o];
        __syncthreads();
        if (tid >= o) scn[tid] += t;
        __syncthreads();
    }
    int ex = off + scn[tid] - deg;
    const int node = (b << BSHIFT) + tid;
    if (node < N) {
        rowptr[node] = ex;
        dinv[node] = rsqrtf((float)deg + 1.0f);  // +1 self-loop
    }
    scn[tid] = ex;
    __syncthreads();
    for (int e = off + tid; e < end; e += THREADS) {
        int p = ePack[e];
        int pos = atomicAdd(&scn[((unsigned)p) >> 20], 1);
        col[pos] = p & 0xFFFFF;
    }
}

// ---- Aggregation F=64: one oct (8 lanes) per row, 4 edges in flight -------

template <bool ACT, bool OUTH>
__global__ __launch_bounds__(THREADS) void agg64g_kernel(
    const __half* __restrict__ g, const int* __restrict__ rowptr,
    const int* __restrict__ col, const float* __restrict__ dinv,
    const float* __restrict__ bias, void* __restrict__ outv, int N) {
    const int tid = threadIdx.x;
    const int lane = tid & 63, wave = tid >> 6;
    const int oct = lane >> 3, sub = lane & 7;
    const int r = blockIdx.x * 32 + wave * 8 + oct;
    const uint4* __restrict__ g4 = (const uint4*)g;  // 8 uint4 per row
    const bool valid = (r < N);
    int start = 0, end = 0;
    if (valid) { start = rowptr[r]; end = rowptr[r + 1]; }

    float acc[8] = {0.f, 0.f, 0.f, 0.f, 0.f, 0.f, 0.f, 0.f};
    if (valid) add8(acc, g4[(size_t)r * 8 + sub]);  // self-loop

    int e = start;
    for (; e + 4 <= end; e += 4) {
        int c0 = col[e], c1 = col[e + 1], c2 = col[e + 2], c3 = col[e + 3];
        uint4 u0 = g4[(size_t)c0 * 8 + sub];
        uint4 u1 = g4[(size_t)c1 * 8 + sub];
        uint4 u2 = g4[(size_t)c2 * 8 + sub];
        uint4 u3 = g4[(size_t)c3 * 8 + sub];
        add8(acc, u0); add8(acc, u1); add8(acc, u2); add8(acc, u3);
    }
    for (; e < end; ++e) add8(acc, g4[(size_t)col[e] * 8 + sub]);

    if (valid) {
        const float dr = dinv[r];
        float res[8];
#pragma unroll
        for (int k = 0; k < 8; ++k) res[k] = acc[k] * dr;
        if constexpr (ACT) {
            const float* bp = bias + sub * 8;
#pragma unroll
            for (int k = 0; k < 8; ++k) res[k] = celu1(res[k] + bp[k]);
        }
        if constexpr (OUTH) {
            __half2 hp[4] = {__floats2half2_rn(res[0], res[1]), __floats2half2_rn(res[2], res[3]),
                             __floats2half2_rn(res[4], res[5]), __floats2half2_rn(res[6], res[7])};
            *(uint4*)((__half*)outv + (size_t)r * 64 + sub * 8) = *(uint4*)hp;
        } else {
            float4* o4 = (float4*)((float*)outv + (size_t)r * 64 + sub * 8);
            o4[0] = make_float4(res[0], res[1], res[2], res[3]);
            o4[1] = make_float4(res[4], res[5], res[6], res[7]);
        }
    }
}

// ---- Aggregation F=128: one 16-lane group per row, 4 edges in flight ------

__global__ __launch_bounds__(THREADS) void agg128g_kernel(
    const __half* __restrict__ g, const int* __restrict__ rowptr,
    const int* __restrict__ col, const float* __restrict__ dinv,
    __half* __restrict__ out, int N) {
    const int tid = threadIdx.x;
    const int lane = tid & 63, wave = tid >> 6;
    const int grp = lane >> 4, sub = lane & 15;
    const int r = blockIdx.x * 16 + wave * 4 + grp;
    const uint4* __restrict__ g4 = (const uint4*)g;  // 16 uint4 per row
    const bool valid = (r < N);
    int start = 0, end = 0;
    if (valid) { start = rowptr[r]; end = rowptr[r + 1]; }

    float acc[8] = {0.f, 0.f, 0.f, 0.f, 0.f, 0.f, 0.f, 0.f};
    if (valid) add8(acc, g4[(size_t)r * 16 + sub]);  // self-loop

    int e = start;
    for (; e + 4 <= end; e += 4) {
        int c0 = col[e], c1 = col[e + 1], c2 = col[e + 2], c3 = col[e + 3];
        uint4 u0 = g4[(size_t)c0 * 16 + sub];
        uint4 u1 = g4[(size_t)c1 * 16 + sub];
        uint4 u2 = g4[(size_t)c2 * 16 + sub];
        uint4 u3 = g4[(size_t)c3 * 16 + sub];
        add8(acc, u0); add8(acc, u1); add8(acc, u2); add8(acc, u3);
    }
    for (; e < end; ++e) add8(acc, g4[(size_t)col[e] * 16 + sub]);

    if (valid) {
        const float dr = dinv[r];
        __half2 hp[4] = {__floats2half2_rn(acc[0] * dr, acc[1] * dr),
                         __floats2half2_rn(acc[2] * dr, acc[3] * dr),
                         __floats2half2_rn(acc[4] * dr, acc[5] * dr),
                         __floats2half2_rn(acc[6] * dr, acc[7] * dr)};
        *(uint4*)(out + (size_t)r * 128 + sub * 8) = *(uint4*)hp;
    }
}

// ---- MFMA dense transform: out[N,F] = [dinv*] act(X @ W + b) --------------

template <int K, int F, bool ACT, bool SCALE>
__global__ __launch_bounds__(THREADS) void mfma_gemm_kernel(
    const __half* __restrict__ X, const __half* __restrict__ Wt,
    const float* __restrict__ bias, const float* __restrict__ dinv,
    __half* __restrict__ outh, int N) {
    constexpr int KP = K + 8;  // padded LDS row stride (halves)
    constexpr int NT = F / 16;
    __shared__ __half Ws[F * KP];

    const int tid = threadIdx.x;
    for (int i = tid; i < F * K / 8; i += THREADS) {
        int f = i / (K / 8), kg = i % (K / 8);
        *(uint4*)&Ws[f * KP + kg * 8] = ((const uint4*)Wt)[i];
    }
    __syncthreads();

    const int wave = tid >> 6, lane = tid & 63;
    const int q = lane >> 4, mn = lane & 15;
    const int row0w = blockIdx.x * 64 + wave * 16;
    int arow = row0w + mn;
    if (arow >= N) arow = N - 1;  // clamp loads; garbage rows masked on store

    floatx4 acc[NT];
#pragma unroll
    for (int t = 0; t < NT; ++t) acc[t] = {0.f, 0.f, 0.f, 0.f};

    const __half* xp = X + (size_t)arow * K + q * 8;
#pragma unroll
    for (int k0 = 0; k0 < K; k0 += 32) {
        half8 a = *(const half8*)(xp + k0);
#pragma unroll
        for (int t = 0; t < NT; ++t) {
            half8 b = *(const half8*)&Ws[(t * 16 + mn) * KP + k0 + q * 8];
            acc[t] = __builtin_amdgcn_mfma_f32_16x16x32_f16(a, b, acc[t], 0, 0, 0);
        }
    }

    // D: reg i <-> row = row0w + q*4 + i, col = t*16 + mn
    const int orow0 = row0w + q * 4;
    float dv[4] = {1.f, 1.f, 1.f, 1.f};
    if constexpr (SCALE) {
#pragma unroll
        for (int i = 0; i < 4; ++i) {
            int r = orow0 + i;
            if (r < N) dv[i] = dinv[r];
        }
    }
#pragma unroll
    for (int t = 0; t < NT; ++t) {
        const int coln = t * 16 + mn;
        float bv = 0.f;
        if constexpr (ACT) bv = bias[coln];
#pragma unroll
        for (int i = 0; i < 4; ++i) {
            int r = orow0 + i;
            if (r < N) {
                float v = acc[t][i];
                if constexpr (ACT) v = celu1(v + bv);
                if constexpr (SCALE) v *= dv[i];
                outh[(size_t)r * F + coln] = __float2half(v);
            }
        }
    }
}

// ---------------------------------------------------------------------------

extern "C" void kernel_launch(void* const* d_in, const int* in_sizes, int n_in,
                              void* d_out, int out_size, void* d_ws, size_t ws_size,
                              hipStream_t stream) {
    const float* x  = (const float*)d_in[0];
    const int*   ei = (const int*)d_in[1];
    const float* W1 = (const float*)d_in[2];
    const float* b1 = (const float*)d_in[3];
    const float* W2 = (const float*)d_in[4];
    const float* b2 = (const float*)d_in[5];
    const float* W3 = (const float*)d_in[6];
    const float* b3 = (const float*)d_in[7];
    float* out = (float*)d_out;

    const int N = in_sizes[0] / 64;   // 100000
    const int E = in_sizes[1] / 2;    // 1600000
    const int* src = ei;
    const int* dst = ei + E;
    const int NBUCK = (N + BNODES - 1) >> BSHIFT;  // 391

    char* p = (char*)d_ws;
    auto carve = [&](size_t bytes) {
        void* q = p;
        p += (bytes + 255) & ~(size_t)255;
        return q;
    };
    int*    rowptr    = (int*)carve((size_t)(N + 1) * sizeof(int));
    int*    col       = (int*)carve((size_t)E * sizeof(int));
    float*  dinv      = (float*)carve((size_t)N * sizeof(float));
    int*    bucketCnt = (int*)carve(NBUCK_MAX * sizeof(int));
    int*    bucketOff = (int*)carve((NBUCK_MAX + 1) * sizeof(int));
    int*    bucketCur = (int*)carve(NBUCK_MAX * sizeof(int));
    __half* xg        = (__half*)carve((size_t)N * 64 * sizeof(__half));
    __half* Wt1       = (__half*)carve(64 * 128 * sizeof(__half));
    __half* Wt2       = (__half*)carve(128 * 128 * sizeof(__half));
    __half* Wt3       = (__half*)carve(128 * 64 * sizeof(__half));
    __half* FA        = (__half*)carve((size_t)N * 128 * sizeof(__half));
    __half* FB        = (__half*)carve((size_t)N * 128 * sizeof(__half));
    int*    ePack     = (int*)FB;  // 6.4MB; consumed by build_kernel before gemm1 writes FB

    const int AB64  = (N + 31) / 32;
    const int AB128 = (N + 15) / 16;
    const int GBM = (N + 63) / 64;
    const int SB = (E + CHUNK - 1) / CHUNK;
    const int n8 = N * 8;
    const int PB = (n8 + THREADS - 1) / THREADS + 128;  // f2h blocks + 128 w2h blocks

    // --- CSR build, then fused precision prep (needs dinv) ---
    hipMemsetAsync(bucketCnt, 0, NBUCK_MAX * sizeof(int), stream);
    bucket_hist_kernel<<<256, THREADS, 0, stream>>>(dst, bucketCnt, E, NBUCK);
    bucket_scan_kernel<<<1, SCANT, 0, stream>>>(bucketCnt, bucketOff, bucketCur, rowptr, NBUCK, N);
    bucket_scatter_kernel<<<SB, THREADS, 0, stream>>>(src, dst, bucketCur, ePack, E, NBUCK);
    build_kernel<<<NBUCK, THREADS, 0, stream>>>(ePack, bucketOff, rowptr, dinv, col, N);
    prep_kernel<<<PB, THREADS, 0, stream>>>(x, dinv, xg, W1, Wt1, W2, Wt2, W3, Wt3, n8);

    // --- Layer 1: s1 = Agg(x);  g1 = dinv*celu(s1@W1+b1)  (pre-scaled) ---
    agg64g_kernel<false, true><<<AB64, THREADS, 0, stream>>>(xg, rowptr, col, dinv, nullptr, FA, N);
    mfma_gemm_kernel<64, 128, true, true><<<GBM, THREADS, 0, stream>>>(FA, Wt1, b1, dinv, FB, N);

    // --- Layer 2: s2 = Agg(g1);  a2 = celu(s2@W2+b2)  (NOT pre-scaled) ---
    agg128g_kernel<<<AB128, THREADS, 0, stream>>>(FB, rowptr, col, dinv, FA, N);
    mfma_gemm_kernel<128, 128, true, false><<<GBM, THREADS, 0, stream>>>(FA, Wt2, b2, dinv, FB, N);

    // --- Layer 3: g3 = dinv*(a2@W3); out = celu(dinv*(g3[r]+sum g3)+b3) ---
    mfma_gemm_kernel<128, 64, false, true><<<GBM, THREADS, 0, stream>>>(FB, Wt3, nullptr, dinv, FA, N);
    agg64g_kernel<true, false><<<AB64, THREADS, 0, stream>>>(FA, rowptr, col, dinv, b3, out, N);
}

// Round 10
// 327.231 us; speedup vs baseline: 2.3909x; 1.0009x over previous
//
#include <hip/hip_runtime.h>
#include <hip/hip_fp16.h>
#include <math.h>

// ---------------------------------------------------------------------------
// 3-layer GCN. R2: bucketed CSR build. R3: fp16 gathers. R4: LDS-only CSR.
// R5: MFMA dense transforms, fp16 buffers. R6: pre-scaled g. R7: oct-per-row
// aggs. R8: unroll-4 gathers, fused prep.
// R9: layer-2 aggregation split into two half-feature passes (64 feats each,
//     8-lane groups) — halves the random L2 working set (25.6->12.8 MB) to
//     raise the L2 hit rate; tests whether beyond-L2 random-line BW is the
//     agg ceiling.
// ---------------------------------------------------------------------------

#define THREADS 256
#define SCANT 512
#define BSHIFT 8               // nodes per bucket = 256
#define BNODES (1 << BSHIFT)
#define NBUCK_MAX 512
#define EPT 16
#define CHUNK (THREADS * EPT)

typedef _Float16 half8 __attribute__((ext_vector_type(8)));
typedef float floatx4 __attribute__((ext_vector_type(4)));

__device__ __forceinline__ float celu1(float v) {
    return v > 0.0f ? v : expm1f(v);
}

__device__ __forceinline__ void add8(float* acc, uint4 u) {
    const __half2* h2 = (const __half2*)&u;
    float2 f;
    f = __half22float2(h2[0]); acc[0] += f.x; acc[1] += f.y;
    f = __half22float2(h2[1]); acc[2] += f.x; acc[3] += f.y;
    f = __half22float2(h2[2]); acc[4] += f.x; acc[5] += f.y;
    f = __half22float2(h2[3]); acc[6] += f.x; acc[7] += f.y;
}

// ---- fused prep: xg = dinv*x (fp16) ; Wt = W^T (fp16) ---------------------

__global__ __launch_bounds__(THREADS) void prep_kernel(
    const float* __restrict__ x, const float* __restrict__ dinv,
    __half* __restrict__ xg,
    const float* __restrict__ W1, __half* __restrict__ Wt1,
    const float* __restrict__ W2, __half* __restrict__ Wt2,
    const float* __restrict__ W3, __half* __restrict__ Wt3, int n8) {
    const int nf2h = (n8 + THREADS - 1) / THREADS;  // blocks for f2h part
    int b = blockIdx.x;
    if (b < nf2h) {
        int i = b * THREADS + threadIdx.x;
        if (i < n8) {
            float d = dinv[i >> 3];
            float4 a = ((const float4*)x)[i * 2];
            float4 c = ((const float4*)x)[i * 2 + 1];
            __half2 h[4] = {__floats2half2_rn(a.x * d, a.y * d), __floats2half2_rn(a.z * d, a.w * d),
                            __floats2half2_rn(c.x * d, c.y * d), __floats2half2_rn(c.z * d, c.w * d)};
            ((uint4*)xg)[i] = *(uint4*)h;
        }
        return;
    }
    b -= nf2h;
    const float* W; __half* Wt; int K, F;
    if (b < 32)      { W = W1; Wt = Wt1; K = 64;  F = 128; }
    else if (b < 96) { W = W2; Wt = Wt2; K = 128; F = 128; b -= 32; }
    else             { W = W3; Wt = Wt3; K = 128; F = 64;  b -= 96; }
    int i = b * THREADS + threadIdx.x;
    if (i < K * F) {
        int k = i / F, f = i % F;
        Wt[f * K + k] = __float2half(W[i]);
    }
}

// ---- CSR build: bucketed counting sort, LDS-atomic only -------------------

__global__ __launch_bounds__(THREADS) void bucket_hist_kernel(
    const int* __restrict__ dst, int* __restrict__ bucketCnt, int E, int NBUCK) {
    __shared__ int lcnt[NBUCK_MAX];
    for (int i = threadIdx.x; i < NBUCK; i += THREADS) lcnt[i] = 0;
    __syncthreads();
    const int E4 = E >> 2;
    for (int e4 = blockIdx.x * THREADS + threadIdx.x; e4 < E4; e4 += gridDim.x * THREADS) {
        int4 d = ((const int4*)dst)[e4];
        atomicAdd(&lcnt[d.x >> BSHIFT], 1);
        atomicAdd(&lcnt[d.y >> BSHIFT], 1);
        atomicAdd(&lcnt[d.z >> BSHIFT], 1);
        atomicAdd(&lcnt[d.w >> BSHIFT], 1);
    }
    if (blockIdx.x == 0) {
        for (int e = (E4 << 2) + threadIdx.x; e < E; e += THREADS)
            atomicAdd(&lcnt[dst[e] >> BSHIFT], 1);
    }
    __syncthreads();
    for (int i = threadIdx.x; i < NBUCK; i += THREADS)
        if (lcnt[i]) atomicAdd(&bucketCnt[i], lcnt[i]);
}

__global__ __launch_bounds__(SCANT) void bucket_scan_kernel(
    const int* __restrict__ bucketCnt, int* __restrict__ bucketOff,
    int* __restrict__ bucketCur, int* __restrict__ rowptr, int NBUCK, int N) {
    __shared__ int s[SCANT];
    const int tid = threadIdx.x;
    int v = (tid < NBUCK) ? bucketCnt[tid] : 0;
    s[tid] = v;
    __syncthreads();
    for (int off = 1; off < SCANT; off <<= 1) {
        int t = 0;
        if (tid >= off) t = s[tid - off];
        __syncthreads();
        if (tid >= off) s[tid] += t;
        __syncthreads();
    }
    if (tid < NBUCK) {
        int ex = s[tid] - v;
        bucketOff[tid] = ex;
        bucketCur[tid] = ex;
    }
    if (tid == 0) {
        int total = s[SCANT - 1];
        bucketOff[NBUCK] = total;  // == E
        rowptr[N] = total;
    }
}

// packed edge record: (dst & (BNODES-1)) << 20 | src   (valid: N < 2^20)
__global__ __launch_bounds__(THREADS) void bucket_scatter_kernel(
    const int* __restrict__ src, const int* __restrict__ dst,
    int* __restrict__ bucketCur, int* __restrict__ ePack, int E, int NBUCK) {
    __shared__ int lcnt[NBUCK_MAX];
    __shared__ int lbase[NBUCK_MAX];
    for (int i = threadIdx.x; i < NBUCK; i += THREADS) lcnt[i] = 0;
    __syncthreads();
    const int base = blockIdx.x * CHUNK;
    int bk[EPT], rk[EPT], pk[EPT];
#pragma unroll
    for (int i = 0; i < EPT; ++i) {
        int e = base + i * THREADS + threadIdx.x;
        if (e < E) {
            int d = dst[e];
            pk[i] = ((d & (BNODES - 1)) << 20) | src[e];
            bk[i] = d >> BSHIFT;
            rk[i] = atomicAdd(&lcnt[bk[i]], 1);
        } else {
            bk[i] = -1;
        }
    }
    __syncthreads();
    for (int i = threadIdx.x; i < NBUCK; i += THREADS)
        if (lcnt[i]) lbase[i] = atomicAdd(&bucketCur[i], lcnt[i]);
    __syncthreads();
#pragma unroll
    for (int i = 0; i < EPT; ++i) {
        if (bk[i] >= 0) ePack[lbase[bk[i]] + rk[i]] = pk[i];
    }
}

// one block per bucket: LDS hist -> LDS scan -> rowptr/dinv/col
__global__ __launch_bounds__(THREADS) void build_kernel(
    const int* __restrict__ ePack, const int* __restrict__ bucketOff,
    int* __restrict__ rowptr, float* __restrict__ dinv,
    int* __restrict__ col, int N) {
    __shared__ int hist[BNODES];
    __shared__ int scn[BNODES];
    const int tid = threadIdx.x;
    const int b = blockIdx.x;
    const int off = bucketOff[b];
    const int end = bucketOff[b + 1];
    hist[tid] = 0;
    __syncthreads();
    for (int e = off + tid; e < end; e += THREADS)
        atomicAdd(&hist[((unsigned)ePack[e]) >> 20], 1);
    __syncthreads();
    int deg = hist[tid];
    scn[tid] = deg;
    __syncthreads();
    for (int o = 1; o < BNODES; o <<= 1) {
        int t = 0;
        if (tid >= o) t = scn[tid - o];
        __syncthreads();
        if (tid >= o) scn[tid] += t;
        __syncthreads();
    }
    int ex = off + scn[tid] - deg;
    const int node = (b << BSHIFT) + tid;
    if (node < N) {
        rowptr[node] = ex;
        dinv[node] = rsqrtf((float)deg + 1.0f);  // +1 self-loop
    }
    scn[tid] = ex;
    __syncthreads();
    for (int e = off + tid; e < end; e += THREADS) {
        int p = ePack[e];
        int pos = atomicAdd(&scn[((unsigned)p) >> 20], 1);
        col[pos] = p & 0xFFFFF;
    }
}

// ---- Aggregation F=64: one oct (8 lanes) per row, 4 edges in flight -------

template <bool ACT, bool OUTH>
__global__ __launch_bounds__(THREADS) void agg64g_kernel(
    const __half* __restrict__ g, const int* __restrict__ rowptr,
    const int* __restrict__ col, const float* __restrict__ dinv,
    const float* __restrict__ bias, void* __restrict__ outv, int N) {
    const int tid = threadIdx.x;
    const int lane = tid & 63, wave = tid >> 6;
    const int oct = lane >> 3, sub = lane & 7;
    const int r = blockIdx.x * 32 + wave * 8 + oct;
    const uint4* __restrict__ g4 = (const uint4*)g;  // 8 uint4 per row
    const bool valid = (r < N);
    int start = 0, end = 0;
    if (valid) { start = rowptr[r]; end = rowptr[r + 1]; }

    float acc[8] = {0.f, 0.f, 0.f, 0.f, 0.f, 0.f, 0.f, 0.f};
    if (valid) add8(acc, g4[(size_t)r * 8 + sub]);  // self-loop

    int e = start;
    for (; e + 4 <= end; e += 4) {
        int c0 = col[e], c1 = col[e + 1], c2 = col[e + 2], c3 = col[e + 3];
        uint4 u0 = g4[(size_t)c0 * 8 + sub];
        uint4 u1 = g4[(size_t)c1 * 8 + sub];
        uint4 u2 = g4[(size_t)c2 * 8 + sub];
        uint4 u3 = g4[(size_t)c3 * 8 + sub];
        add8(acc, u0); add8(acc, u1); add8(acc, u2); add8(acc, u3);
    }
    for (; e < end; ++e) add8(acc, g4[(size_t)col[e] * 8 + sub]);

    if (valid) {
        const float dr = dinv[r];
        float res[8];
#pragma unroll
        for (int k = 0; k < 8; ++k) res[k] = acc[k] * dr;
        if constexpr (ACT) {
            const float* bp = bias + sub * 8;
#pragma unroll
            for (int k = 0; k < 8; ++k) res[k] = celu1(res[k] + bp[k]);
        }
        if constexpr (OUTH) {
            __half2 hp[4] = {__floats2half2_rn(res[0], res[1]), __floats2half2_rn(res[2], res[3]),
                             __floats2half2_rn(res[4], res[5]), __floats2half2_rn(res[6], res[7])};
            *(uint4*)((__half*)outv + (size_t)r * 64 + sub * 8) = *(uint4*)hp;
        } else {
            float4* o4 = (float4*)((float*)outv + (size_t)r * 64 + sub * 8);
            o4[0] = make_float4(res[0], res[1], res[2], res[3]);
            o4[1] = make_float4(res[4], res[5], res[6], res[7]);
        }
    }
}

// ---- Aggregation F=128, two half-feature passes ---------------------------
// 8-lane oct per (row, half): pass working set 12.8 MB (vs 25.6) for L2.
// blockIdx >= NB selects the upper feature half.

__global__ __launch_bounds__(THREADS) void agg128g_kernel(
    const __half* __restrict__ g, const int* __restrict__ rowptr,
    const int* __restrict__ col, const float* __restrict__ dinv,
    __half* __restrict__ out, int N, int NB) {
    const int tid = threadIdx.x;
    const int lane = tid & 63, wave = tid >> 6;
    const int oct = lane >> 3, sub = lane & 7;
    int bx = blockIdx.x;
    int half = 0;
    if (bx >= NB) { half = 1; bx -= NB; }
    const int r = bx * 32 + wave * 8 + oct;
    // pre-offset by feature half + sub; row stride = 16 uint4 (128 halves)
    const uint4* __restrict__ g4 = (const uint4*)g + half * 8 + sub;
    const bool valid = (r < N);
    int start = 0, end = 0;
    if (valid) { start = rowptr[r]; end = rowptr[r + 1]; }

    float acc[8] = {0.f, 0.f, 0.f, 0.f, 0.f, 0.f, 0.f, 0.f};
    if (valid) add8(acc, g4[(size_t)r * 16]);  // self-loop

    int e = start;
    for (; e + 4 <= end; e += 4) {
        int c0 = col[e], c1 = col[e + 1], c2 = col[e + 2], c3 = col[e + 3];
        uint4 u0 = g4[(size_t)c0 * 16];
        uint4 u1 = g4[(size_t)c1 * 16];
        uint4 u2 = g4[(size_t)c2 * 16];
        uint4 u3 = g4[(size_t)c3 * 16];
        add8(acc, u0); add8(acc, u1); add8(acc, u2); add8(acc, u3);
    }
    for (; e < end; ++e) add8(acc, g4[(size_t)col[e] * 16]);

    if (valid) {
        const float dr = dinv[r];
        __half2 hp[4] = {__floats2half2_rn(acc[0] * dr, acc[1] * dr),
                         __floats2half2_rn(acc[2] * dr, acc[3] * dr),
                         __floats2half2_rn(acc[4] * dr, acc[5] * dr),
                         __floats2half2_rn(acc[6] * dr, acc[7] * dr)};
        *(uint4*)(out + (size_t)r * 128 + half * 64 + sub * 8) = *(uint4*)hp;
    }
}

// ---- MFMA dense transform: out[N,F] = [dinv*] act(X @ W + b) --------------

template <int K, int F, bool ACT, bool SCALE>
__global__ __launch_bounds__(THREADS) void mfma_gemm_kernel(
    const __half* __restrict__ X, const __half* __restrict__ Wt,
    const float* __restrict__ bias, const float* __restrict__ dinv,
    __half* __restrict__ outh, int N) {
    constexpr int KP = K + 8;  // padded LDS row stride (halves)
    constexpr int NT = F / 16;
    __shared__ __half Ws[F * KP];

    const int tid = threadIdx.x;
    for (int i = tid; i < F * K / 8; i += THREADS) {
        int f = i / (K / 8), kg = i % (K / 8);
        *(uint4*)&Ws[f * KP + kg * 8] = ((const uint4*)Wt)[i];
    }
    __syncthreads();

    const int wave = tid >> 6, lane = tid & 63;
    const int q = lane >> 4, mn = lane & 15;
    const int row0w = blockIdx.x * 64 + wave * 16;
    int arow = row0w + mn;
    if (arow >= N) arow = N - 1;  // clamp loads; garbage rows masked on store

    floatx4 acc[NT];
#pragma unroll
    for (int t = 0; t < NT; ++t) acc[t] = {0.f, 0.f, 0.f, 0.f};

    const __half* xp = X + (size_t)arow * K + q * 8;
#pragma unroll
    for (int k0 = 0; k0 < K; k0 += 32) {
        half8 a = *(const half8*)(xp + k0);
#pragma unroll
        for (int t = 0; t < NT; ++t) {
            half8 b = *(const half8*)&Ws[(t * 16 + mn) * KP + k0 + q * 8];
            acc[t] = __builtin_amdgcn_mfma_f32_16x16x32_f16(a, b, acc[t], 0, 0, 0);
        }
    }

    // D: reg i <-> row = row0w + q*4 + i, col = t*16 + mn
    const int orow0 = row0w + q * 4;
    float dv[4] = {1.f, 1.f, 1.f, 1.f};
    if constexpr (SCALE) {
#pragma unroll
        for (int i = 0; i < 4; ++i) {
            int r = orow0 + i;
            if (r < N) dv[i] = dinv[r];
        }
    }
#pragma unroll
    for (int t = 0; t < NT; ++t) {
        const int coln = t * 16 + mn;
        float bv = 0.f;
        if constexpr (ACT) bv = bias[coln];
#pragma unroll
        for (int i = 0; i < 4; ++i) {
            int r = orow0 + i;
            if (r < N) {
                float v = acc[t][i];
                if constexpr (ACT) v = celu1(v + bv);
                if constexpr (SCALE) v *= dv[i];
                outh[(size_t)r * F + coln] = __float2half(v);
            }
        }
    }
}

// ---------------------------------------------------------------------------

extern "C" void kernel_launch(void* const* d_in, const int* in_sizes, int n_in,
                              void* d_out, int out_size, void* d_ws, size_t ws_size,
                              hipStream_t stream) {
    const float* x  = (const float*)d_in[0];
    const int*   ei = (const int*)d_in[1];
    const float* W1 = (const float*)d_in[2];
    const float* b1 = (const float*)d_in[3];
    const float* W2 = (const float*)d_in[4];
    const float* b2 = (const float*)d_in[5];
    const float* W3 = (const float*)d_in[6];
    const float* b3 = (const float*)d_in[7];
    float* out = (float*)d_out;

    const int N = in_sizes[0] / 64;   // 100000
    const int E = in_sizes[1] / 2;    // 1600000
    const int* src = ei;
    const int* dst = ei + E;
    const int NBUCK = (N + BNODES - 1) >> BSHIFT;  // 391

    char* p = (char*)d_ws;
    auto carve = [&](size_t bytes) {
        void* q = p;
        p += (bytes + 255) & ~(size_t)255;
        return q;
    };
    int*    rowptr    = (int*)carve((size_t)(N + 1) * sizeof(int));
    int*    col       = (int*)carve((size_t)E * sizeof(int));
    float*  dinv      = (float*)carve((size_t)N * sizeof(float));
    int*    bucketCnt = (int*)carve(NBUCK_MAX * sizeof(int));
    int*    bucketOff = (int*)carve((NBUCK_MAX + 1) * sizeof(int));
    int*    bucketCur = (int*)carve(NBUCK_MAX * sizeof(int));
    __half* xg        = (__half*)carve((size_t)N * 64 * sizeof(__half));
    __half* Wt1       = (__half*)carve(64 * 128 * sizeof(__half));
    __half* Wt2       = (__half*)carve(128 * 128 * sizeof(__half));
    __half* Wt3       = (__half*)carve(128 * 64 * sizeof(__half));
    __half* FA        = (__half*)carve((size_t)N * 128 * sizeof(__half));
    __half* FB        = (__half*)carve((size_t)N * 128 * sizeof(__half));
    int*    ePack     = (int*)FB;  // 6.4MB; consumed by build_kernel before gemm1 writes FB

    const int AB64  = (N + 31) / 32;
    const int AB128 = (N + 31) / 32;  // 32 rows/block per half-pass
    const int GBM = (N + 63) / 64;
    const int SB = (E + CHUNK - 1) / CHUNK;
    const int n8 = N * 8;
    const int PB = (n8 + THREADS - 1) / THREADS + 128;  // f2h blocks + 128 w2h blocks

    // --- CSR build, then fused precision prep (needs dinv) ---
    hipMemsetAsync(bucketCnt, 0, NBUCK_MAX * sizeof(int), stream);
    bucket_hist_kernel<<<256, THREADS, 0, stream>>>(dst, bucketCnt, E, NBUCK);
    bucket_scan_kernel<<<1, SCANT, 0, stream>>>(bucketCnt, bucketOff, bucketCur, rowptr, NBUCK, N);
    bucket_scatter_kernel<<<SB, THREADS, 0, stream>>>(src, dst, bucketCur, ePack, E, NBUCK);
    build_kernel<<<NBUCK, THREADS, 0, stream>>>(ePack, bucketOff, rowptr, dinv, col, N);
    prep_kernel<<<PB, THREADS, 0, stream>>>(x, dinv, xg, W1, Wt1, W2, Wt2, W3, Wt3, n8);

    // --- Layer 1: s1 = Agg(x);  g1 = dinv*celu(s1@W1+b1)  (pre-scaled) ---
    agg64g_kernel<false, true><<<AB64, THREADS, 0, stream>>>(xg, rowptr, col, dinv, nullptr, FA, N);
    mfma_gemm_kernel<64, 128, true, true><<<GBM, THREADS, 0, stream>>>(FA, Wt1, b1, dinv, FB, N);

    // --- Layer 2: s2 = Agg(g1) (two half-feature passes);  a2 = celu(s2@W2+b2) ---
    agg128g_kernel<<<2 * AB128, THREADS, 0, stream>>>(FB, rowptr, col, dinv, FA, N, AB128);
    mfma_gemm_kernel<128, 128, true, false><<<GBM, THREADS, 0, stream>>>(FA, Wt2, b2, dinv, FB, N);

    // --- Layer 3: g3 = dinv*(a2@W3); out = celu(dinv*(g3[r]+sum g3)+b3) ---
    mfma_gemm_kernel<128, 64, false, true><<<GBM, THREADS, 0, stream>>>(FB, Wt3, nullptr, dinv, FA, N);
    agg64g_kernel<true, false><<<AB64, THREADS, 0, stream>>>(FA, rowptr, col, dinv, b3, out, N);
}